// Round 1
// baseline (909.803 us; speedup 1.0000x reference)
//
#include <hip/hip_runtime.h>
#include <cstdint>
#include <cstddef>

// QRNN fused pipeline for MI355X (gfx950).
// B=32, S=2048, D_in=512, D_model=1024, D_mlp=1024, n_cls=128.
//
// ws layout (bytes): U bf16 [2048][1024] @0 (4MB) | Fagg @4MB | Zagg @6MB |
//   h @8MB | q0 @8MB+256K | q1 @8MB+512K | zero page @12MB (4KB) | xb bf16 @16MB (64MB)
//
// qrnn_main8: 256x256 tile per (b, 256-step chunk, 128 d), 8 waves (2Mx4N),
// BK=32, ring-4 LDS (4 slots x (A 16KB + B 16KB) = 128KB), global_load_lds
// staging 3 K-steps ahead, counted s_waitcnt vmcnt(8) at K-step boundaries
// (never drained in steady state), 2 phases x 16 MFMA per K-step with raw
// s_barrier + s_setprio around each MFMA cluster (T2+T3+T4+T5 stack).
// LDS conflict-freedom: slot swizzle s^=(row>>1)&3 applied on the *global
// source address* (gload_lds dest must stay linear, rule #21) and on reads.
// xprev shift handled structurally: ksteps 0..15 pair x[t] with U k<512 (W),
// ksteps 16..31 pair x[t-1] with U k>=512 (V); t=-1 reads the zero page.

typedef __attribute__((ext_vector_type(8))) short short8;
typedef __attribute__((ext_vector_type(4))) float f32x4;

#define ZERO_OFF_E 6291456u    // 12MB / 2 (bf16 elements)
#define XB_OFF_E   8388608u    // 16MB / 2
#define U_LDS_BASE 8256        // (old fallback kernel) A stage = 129 rows * 64B

__device__ __forceinline__ unsigned short f2bf(float f) {
  unsigned int u = __float_as_uint(f);
  u += 0x7fffu + ((u >> 16) & 1u);
  return (unsigned short)(u >> 16);
}

__device__ __forceinline__ unsigned stage_addr(int r, int c) {
  return (unsigned)(r * 64 + (((c + r + (r >> 2)) & 3) << 4));
}

__device__ __forceinline__ float sigmoidf_fast(float x) {
  return 1.f / (1.f + __expf(-x));
}
__device__ __forceinline__ float tanhf_fast(float x) {
  float a = fabsf(x);
  float e = __expf(-2.f * a);
  float t = (1.f - e) / (1.f + e);
  return copysignf(t, x);
}

// async 16B global->LDS. LDS dest must be wave-uniform base; lane lands at
// base + lane*16. AS casts via integer (low 32 bits of a generic LDS VA are
// the LDS offset; aperture base is 2^32-aligned) - CK-style, compiles clean.
__device__ __forceinline__ void gload_lds16(const void* g, const char* lds) {
  __builtin_amdgcn_global_load_lds(
      (const __attribute__((address_space(1))) void*)(uintptr_t)g,
      (__attribute__((address_space(3))) void*)(uint32_t)(uintptr_t)lds, 16, 0, 0);
}

// ---------------- prologue ----------------
// grid 8833: [0,8192) pack_x (4 float4/thread); [8192,8704) pack_u; [8704,8832) init; 8832 zpg
__global__ void prologue_kernel(const float* __restrict__ x, const float* __restrict__ W,
                                const float* __restrict__ V,
                                const float* __restrict__ b0, const float* __restrict__ b1,
                                const float* __restrict__ b2,
                                unsigned short* __restrict__ xb, unsigned short* __restrict__ U,
                                float* __restrict__ q0, float* __restrict__ q1,
                                float* __restrict__ out, uint4* __restrict__ zpg) {
  __shared__ float T[64 * 65];
  const int bx = blockIdx.x;
  if (bx < 8192) {
    int base = bx * 1024 + threadIdx.x;
#pragma unroll
    for (int i = 0; i < 4; ++i) {
      int gid = base + i * 256;
      float4 v = ((const float4*)x)[gid];
      ushort4 o;
      o.x = f2bf(v.x); o.y = f2bf(v.y); o.z = f2bf(v.z); o.w = f2bf(v.w);
      ((ushort4*)xb)[gid] = o;
    }
  } else if (bx < 8704) {
    const int u = bx - 8192;
    const int j0 = (u & 31) * 64;
    const int k0 = (u >> 5) * 64;
    const int jl = threadIdx.x & 63;
    const int q  = threadIdx.x >> 6;
    const float* src = (k0 < 512) ? (W + (size_t)k0 * 3072) : (V + (size_t)(k0 - 512) * 3072);
#pragma unroll 4
    for (int i = 0; i < 16; ++i) {
      int kl = q * 16 + i;
      T[kl * 65 + jl] = src[(size_t)kl * 3072 + j0 + jl];
    }
    __syncthreads();
    const int kl = threadIdx.x & 63;
#pragma unroll 4
    for (int i = 0; i < 16; ++i) {
      int jj = q * 16 + i;
      U[(size_t)(j0 + jj) * 1024 + k0 + kl] = f2bf(T[kl * 65 + jj]);
    }
  } else if (bx < 8832) {
    int gid = (bx - 8704) * 256 + threadIdx.x;   // 32768
    q0[gid] = b0[gid & 1023];
    q1[gid] = b1[gid & 1023];
    if (gid < 4096) out[gid] = b2[gid & 127];
  } else {
    zpg[threadIdx.x] = make_uint4(0u, 0u, 0u, 0u);   // 4 KB zeros
  }
}

// ---------------- main (bf16 path): 256^2 8-wave phase-split pipeline ----------------
// grid (8 dt, 8 cj, 32 b), block 512 (waves: wm=wid>>2 in {0,1} x wn=wid&3 in {0..3})
// per wave: 128 t-rows x 64 cols -> acc[8][4] f32x4.
__global__ __launch_bounds__(512, 2) void qrnn_main8(
    const unsigned short* __restrict__ wsb, const float* __restrict__ Vb,
    float* __restrict__ Fagg, float* __restrict__ Zagg) {
  __shared__ __align__(16) char smem[131072];

  const int dt = blockIdx.x;
  const int cj = blockIdx.y;
  const int b  = blockIdx.z;
  const int tid = threadIdx.x;
  const int lane = tid & 63;
  const int wid  = tid >> 6;
  const int wm = wid >> 2, wn = wid & 3;
  const int l15 = lane & 15, lc = lane >> 4;
  const int s0 = cj * 256;

  f32x4 acc[8][4];
#pragma unroll
  for (int i = 0; i < 8; ++i)
#pragma unroll
    for (int j = 0; j < 4; ++j) acc[i][j] = f32x4{0.f, 0.f, 0.f, 0.f};

  // ---- per-lane staging source offsets (bf16 elements rel. wsb) ----
  // wave w stages A rows [w*32,w*32+32) and B rows same, 2 instr each (16 rows/instr).
  // lane l -> row_g = base + (l>>2), phys slot p = l&3; source uses logical slot
  // q = p ^ ((row_g>>1)&3) so that swizzled reads see linear data (involution).
  unsigned eAx[2], eAp[2], eB[2];
#pragma unroll
  for (int i = 0; i < 2; ++i) {
    int row_g = wid * 32 + i * 16 + (lane >> 2);
    int q = (lane & 3) ^ ((row_g >> 1) & 3);
    int tx = s0 + row_g;                       // ksteps 0..15: x[t]
    eAx[i] = XB_OFF_E + (unsigned)(b * 2048 + tx) * 512u + (unsigned)(q * 8);
    int tp = s0 - 1 + row_g;                   // ksteps 16..31: x[t-1]
    eAp[i] = (tp < 0) ? (ZERO_OFF_E + (unsigned)(q * 8))
                      : (XB_OFF_E + (unsigned)(b * 2048 + tp) * 512u + (unsigned)(q * 8));
    int jj = (row_g < 128) ? (dt * 128 + row_g) : (1024 + dt * 128 + (row_g - 128));
    eB[i] = (unsigned)jj * 1024u + (unsigned)(q * 8);
  }

  // ---- fragment read offsets (swizzle lc ^ ((l15>>1)&3); invariant under mt/nt*16) ----
  const unsigned swz = (unsigned)((lc ^ ((l15 >> 1) & 3)) << 4);
  const unsigned oA = (unsigned)((wm * 128 + l15) * 64) + swz;            // A rows
  const unsigned oB = 16384u + (unsigned)((wn * 64 + l15) * 64) + swz;    // B rows

  auto stage = [&](int kt) {
    const unsigned sbase = (unsigned)((kt & 3) << 15);
    const unsigned kaddB = (unsigned)(kt * 32);
    const unsigned kaddA = (kt < 16) ? kaddB : (unsigned)((kt - 16) * 32);
    const bool xp = (kt < 16);
#pragma unroll
    for (int i = 0; i < 2; ++i) {
      unsigned da = (unsigned)__builtin_amdgcn_readfirstlane(
          (int)(sbase + (unsigned)(wid * 2048 + i * 1024)));
      const unsigned short* src = wsb + ((xp ? eAx[i] : eAp[i]) + kaddA);
      gload_lds16(src, smem + da);
    }
#pragma unroll
    for (int i = 0; i < 2; ++i) {
      unsigned db = (unsigned)__builtin_amdgcn_readfirstlane(
          (int)(sbase + 16384u + (unsigned)(wid * 2048 + i * 1024)));
      const unsigned short* src = wsb + (eB[i] + kaddB);
      gload_lds16(src, smem + db);
    }
  };

  // ---- pipeline prologue: 3 K-steps in flight; wait slot0 (12 issued, keep 8) ----
  stage(0); stage(1); stage(2);
  asm volatile("s_waitcnt vmcnt(8)" ::: "memory");
  __builtin_amdgcn_s_barrier();
  __builtin_amdgcn_sched_barrier(0);

#pragma unroll 1
  for (int kt = 0; kt < 32; ++kt) {
    const char* buf = smem + ((kt & 3) << 15);
    short8 bfr[4], afr[4];
    // ===== phase 0: B-frags + A-frags mt0-3, issue stage(kt+3), 16 MFMA =====
#pragma unroll
    for (int nt = 0; nt < 4; ++nt) bfr[nt] = *(const short8*)(buf + oB + nt * 1024);
#pragma unroll
    for (int m = 0; m < 4; ++m) afr[m] = *(const short8*)(buf + oA + m * 1024);
    if (kt < 29) stage(kt + 3);     // slot (kt+3)&3 == (kt-1)&3: readers done at last boundary
    __builtin_amdgcn_s_barrier();
    __builtin_amdgcn_s_setprio(1);
#pragma unroll
    for (int m = 0; m < 4; ++m)
#pragma unroll
      for (int nt = 0; nt < 4; ++nt)
        acc[m][nt] = __builtin_amdgcn_mfma_f32_16x16x32_bf16(afr[m], bfr[nt], acc[m][nt], 0, 0, 0);
    __builtin_amdgcn_s_setprio(0);
    __builtin_amdgcn_s_barrier();
    // ===== phase 1: A-frags mt4-7, 16 MFMA =====
#pragma unroll
    for (int m = 0; m < 4; ++m) afr[m] = *(const short8*)(buf + oA + (m + 4) * 1024);
    __builtin_amdgcn_s_barrier();
    __builtin_amdgcn_s_setprio(1);
#pragma unroll
    for (int m = 0; m < 4; ++m)
#pragma unroll
      for (int nt = 0; nt < 4; ++nt)
        acc[m + 4][nt] =
            __builtin_amdgcn_mfma_f32_16x16x32_bf16(afr[m], bfr[nt], acc[m + 4][nt], 0, 0, 0);
    __builtin_amdgcn_s_setprio(0);
    // K-step boundary: guarantee slot (kt+1) landed; keep stages kt+2,kt+3 in flight.
    if (kt <= 28)      asm volatile("s_waitcnt vmcnt(8)" ::: "memory");
    else if (kt == 29) asm volatile("s_waitcnt vmcnt(4)" ::: "memory");
    else               asm volatile("s_waitcnt vmcnt(0)" ::: "memory");
    __builtin_amdgcn_s_barrier();
    __builtin_amdgcn_sched_barrier(0);
  }

  // ---- fused activations + scan: 4 phases of 64 timesteps, 128 d ----
  float* fA   = (float*)smem;                    // [64][132]
  float* tzA  = (float*)(smem + 33792);          // [64][132]
  float* segF = (float*)(smem + 67584);          // [4][128]
  float* segZ = (float*)(smem + 69632);          // [4][128]

  float vb[4];
#pragma unroll
  for (int nt = 0; nt < 4; ++nt)
    vb[nt] = Vb[(wn >> 1) * 1024 + dt * 128 + (wn & 1) * 64 + nt * 16 + l15];

  const int d = tid & 127;
  const int seg = tid >> 7;
  float F_run = 1.f, Z_run = 0.f;

  for (int ph = 0; ph < 4; ++ph) {
    __syncthreads();
    if (wm == (ph >> 1)) {
      float* dst = (wn < 2) ? fA : tzA;
#pragma unroll
      for (int m = 0; m < 4; ++m) {
        const int mt = (ph & 1) * 4 + m;
#pragma unroll
        for (int nt = 0; nt < 4; ++nt)
#pragma unroll
          for (int rg = 0; rg < 4; ++rg) {
            int t = m * 16 + (lc << 2) + rg;          // phase-local 0..63
            int c = (wn & 1) * 64 + nt * 16 + l15;    // 0..127
            float v = acc[mt][nt][rg] + vb[nt];
            v = (wn < 2) ? sigmoidf_fast(v) : tanhf_fast(v);
            dst[t * 132 + c] = v;
          }
      }
    }
    __syncthreads();
    {
      float F = 1.f, Z = 0.f;
#pragma unroll 4
      for (int i = 0; i < 16; ++i) {
        int t = seg * 16 + i;
        float f  = fA[t * 132 + d];
        float tz = tzA[t * 132 + d];
        float z = (1.f - f) * tz;
        Z = f * Z + z;
        F *= f;
      }
      segF[seg * 128 + d] = F;
      segZ[seg * 128 + d] = Z;
    }
    __syncthreads();
    if (tid < 128) {
#pragma unroll
      for (int sgi = 0; sgi < 4; ++sgi) {
        float Fs = segF[sgi * 128 + tid], Zs = segZ[sgi * 128 + tid];
        Z_run = Fs * Z_run + Zs;
        F_run *= Fs;
      }
    }
  }
  if (tid < 128) {
    size_t o = (((size_t)b * 8 + cj) << 10) + dt * 128 + tid;
    Fagg[o] = F_run;
    Zagg[o] = Z_run;
  }
}

// ---------------- fallback (f32 path, 16-chunk layout) — previous verified kernel ----------------
template <bool USE_BF>
__global__ __launch_bounds__(256, 3) void qrnn_main(
    const unsigned short* __restrict__ wsb, const float* __restrict__ xf,
    const float* __restrict__ Vb,
    float* __restrict__ Fagg, float* __restrict__ Zagg) {
  __shared__ __align__(16) char smem[36864];

  const int dt = blockIdx.x;
  const int cj = blockIdx.y;
  const int b  = blockIdx.z;
  const int tid = threadIdx.x;
  const int lane = tid & 63;
  const int wid  = tid >> 6;
  const int wm = wid >> 1, wn = wid & 1;
  const int s0 = cj * 128;
  const int l15 = lane & 15, lc = lane >> 4;

  f32x4 acc[4][4];
#pragma unroll
  for (int i = 0; i < 4; ++i)
#pragma unroll
    for (int j = 0; j < 4; ++j) acc[i][j] = f32x4{0.f, 0.f, 0.f, 0.f};

  unsigned voffA[2];
  size_t offAF[2]; int zAF[2];
#pragma unroll
  for (int p = 0; p < 2; ++p) {
    int cw = tid + p * 256;
    int r = cw >> 2, c = cw & 3;
    int sg = s0 - 1 + r;
    voffA[p] = (sg < 0) ? (ZERO_OFF_E + (unsigned)(c * 8))
                        : (XB_OFF_E + (unsigned)(b * 2048 + sg) * 512u + (unsigned)(c * 8));
    zAF[p] = (sg < 0);
    offAF[p] = ((size_t)(b * 2048 + (sg < 0 ? 0 : sg)) << 9) + c * 8;
  }
  unsigned voffA3 = XB_OFF_E + (unsigned)(b * 2048 + s0 + 127) * 512u + (unsigned)((tid & 3) * 8);
  size_t offAF3 = ((size_t)(b * 2048 + s0 + 127) << 9) + (tid & 3) * 8;

  unsigned voffU[4];
#pragma unroll
  for (int k = 0; k < 4; ++k) {
    int uw = tid + k * 256;
    int r = uw >> 2, c = uw & 3;
    int col = r & 127, half = r >> 7;
    int j = (col < 64) ? (dt * 64 + col) : (1024 + dt * 64 + (col - 64));
    voffU[k] = (unsigned)(j * 1024 + half * 512 + c * 8);
  }

  unsigned wA[2], wU[4];
#pragma unroll
  for (int p = 0; p < 2; ++p) {
    int cw = tid + p * 256;
    wA[p] = stage_addr(cw >> 2, cw & 3);
  }
  const unsigned wA3 = stage_addr(128, tid & 3);
#pragma unroll
  for (int k = 0; k < 4; ++k) {
    int uw = tid + k * 256;
    wU[k] = U_LDS_BASE + stage_addr(uw >> 2, uw & 3);
  }

  unsigned roA[2][4], roU[2][4];
#pragma unroll
  for (int h2 = 0; h2 < 2; ++h2) {
#pragma unroll
    for (int mt = 0; mt < 4; ++mt) {
      int rr = wm * 64 + l15 + mt * 16 + 1 - h2;
      roA[h2][mt] = stage_addr(rr, lc);
    }
#pragma unroll
    for (int nt = 0; nt < 4; ++nt) {
      int rrU = h2 * 128 + wn * 64 + l15 + nt * 16;
      roU[h2][nt] = U_LDS_BASE + stage_addr(rrU, lc);
    }
  }

  uint4 pA0, pA1, pA3, pU0, pU1, pU2, pU3;

  auto load_stage = [&](int s) {
    const unsigned short* cur = wsb + s * 32;
    if constexpr (USE_BF) {
      pA0 = *(const uint4*)(cur + voffA[0]);
      pA1 = *(const uint4*)(cur + voffA[1]);
      if (tid < 4) pA3 = *(const uint4*)(cur + voffA3);
    } else {
      const float* curf = xf + s * 32;
#pragma unroll
      for (int p = 0; p < 2; ++p) {
        uint4 v = make_uint4(0u, 0u, 0u, 0u);
        if (!zAF[p]) {
          float4 a0 = *(const float4*)(curf + offAF[p]);
          float4 a1 = *(const float4*)(curf + offAF[p] + 4);
          v.x = (unsigned)f2bf(a0.x) | ((unsigned)f2bf(a0.y) << 16);
          v.y = (unsigned)f2bf(a0.z) | ((unsigned)f2bf(a0.w) << 16);
          v.z = (unsigned)f2bf(a1.x) | ((unsigned)f2bf(a1.y) << 16);
          v.w = (unsigned)f2bf(a1.z) | ((unsigned)f2bf(a1.w) << 16);
        }
        if (p == 0) pA0 = v; else pA1 = v;
      }
      if (tid < 4) {
        float4 a0 = *(const float4*)(curf + offAF3);
        float4 a1 = *(const float4*)(curf + offAF3 + 4);
        pA3.x = (unsigned)f2bf(a0.x) | ((unsigned)f2bf(a0.y) << 16);
        pA3.y = (unsigned)f2bf(a0.z) | ((unsigned)f2bf(a0.w) << 16);
        pA3.z = (unsigned)f2bf(a1.x) | ((unsigned)f2bf(a1.y) << 16);
        pA3.w = (unsigned)f2bf(a1.z) | ((unsigned)f2bf(a1.w) << 16);
      }
    }
    pU0 = *(const uint4*)(cur + voffU[0]);
    pU1 = *(const uint4*)(cur + voffU[1]);
    pU2 = *(const uint4*)(cur + voffU[2]);
    pU3 = *(const uint4*)(cur + voffU[3]);
  };

  load_stage(0);

#pragma unroll 1
  for (int s = 0; s < 16; ++s) {
    __syncthreads();
    *(uint4*)(smem + wA[0]) = pA0;
    *(uint4*)(smem + wA[1]) = pA1;
    if (tid < 4) *(uint4*)(smem + wA3) = pA3;
    *(uint4*)(smem + wU[0]) = pU0;
    *(uint4*)(smem + wU[1]) = pU1;
    *(uint4*)(smem + wU[2]) = pU2;
    *(uint4*)(smem + wU[3]) = pU3;
    __syncthreads();
    if (s < 15) load_stage(s + 1);
#pragma unroll
    for (int h2 = 0; h2 < 2; ++h2) {
      short8 bfr[4];
#pragma unroll
      for (int nt = 0; nt < 4; ++nt)
        bfr[nt] = *(const short8*)(smem + roU[h2][nt]);
#pragma unroll
      for (int mt = 0; mt < 4; ++mt) {
        short8 afr = *(const short8*)(smem + roA[h2][mt]);
#pragma unroll
        for (int nt = 0; nt < 4; ++nt)
          acc[mt][nt] = __builtin_amdgcn_mfma_f32_16x16x32_bf16(afr, bfr[nt], acc[mt][nt], 0, 0, 0);
      }
    }
  }

  float* fA   = (float*)smem;
  float* tzA  = (float*)(smem + 17408);
  float* segF = (float*)(smem + 34816);
  float* segZ = (float*)(smem + 35840);

  const int d = tid & 63;
  float vb[4];
#pragma unroll
  for (int nt = 0; nt < 4; ++nt)
    vb[nt] = Vb[wn * 1024 + dt * 64 + nt * 16 + l15];

  float F_run = 1.f, Z_run = 0.f;

  for (int ph = 0; ph < 2; ++ph) {
    __syncthreads();
    if (wm == ph) {
      float* dst = (wn == 0) ? fA : tzA;
#pragma unroll
      for (int mt = 0; mt < 4; ++mt)
#pragma unroll
        for (int nt = 0; nt < 4; ++nt)
#pragma unroll
          for (int rg = 0; rg < 4; ++rg) {
            int t = mt * 16 + ((lane >> 4) << 2) + rg;
            int c = nt * 16 + l15;
            float v = acc[mt][nt][rg] + vb[nt];
            v = (wn == 0) ? sigmoidf_fast(v) : tanhf_fast(v);
            dst[t * 68 + c] = v;
          }
    }
    __syncthreads();
    {
      int seg = tid >> 6;
      float F = 1.f, Z = 0.f;
#pragma unroll 4
      for (int i = 0; i < 16; ++i) {
        int t = seg * 16 + i;
        float f  = fA[t * 68 + d];
        float tz = tzA[t * 68 + d];
        float z = (1.f - f) * tz;
        Z = f * Z + z;
        F *= f;
      }
      segF[seg * 64 + d] = F;
      segZ[seg * 64 + d] = Z;
    }
    __syncthreads();
    if (tid < 64) {
#pragma unroll
      for (int sgi = 0; sgi < 4; ++sgi) {
        float Fs = segF[sgi * 64 + tid], Zs = segZ[sgi * 64 + tid];
        Z_run = Fs * Z_run + Zs;
        F_run *= Fs;
      }
    }
  }
  if (tid < 64) {
    size_t o = (((size_t)b * 16 + cj) << 10) + dt * 64 + tid;
    Fagg[o] = F_run;
    Zagg[o] = Z_run;
  }
}

// ---------------- head: K-split o-gate + nch-chunk combine ----------------
// grid (16 dtile, 32 b), block 256 = 64 d x 4 k-segments
__global__ void head_kernel(const float* __restrict__ x, const float* __restrict__ W,
                            const float* __restrict__ V, const float* __restrict__ Vb,
                            const float* __restrict__ Fagg, const float* __restrict__ Zagg,
                            float* __restrict__ h, int nch) {
  __shared__ float red[4][64];
  const int dl = threadIdx.x & 63;
  const int w  = threadIdx.x >> 6;
  const int d = blockIdx.x * 64 + dl;
  const int b = blockIdx.y;

  const float* xl = x + ((size_t)b * 2048 + 2047) * 512;
  const float* xp = xl - 512;
  const float* Wc = W + 2048 + d;
  const float* Vc = V + 2048 + d;
  float po = 0.f;
  const int k0 = w * 128;
#pragma unroll 8
  for (int k = k0; k < k0 + 128; ++k) {
    po += xl[k] * Wc[(size_t)k * 3072];
    po += xp[k] * Vc[(size_t)k * 3072];
  }
  red[w][dl] = po;
  __syncthreads();
  if (w == 0) {
    po = red[0][dl] + red[1][dl] + red[2][dl] + red[3][dl] + Vb[2048 + d];
    float c = 0.f;
    for (int j = 0; j < nch; ++j) {
      size_t o = (((size_t)b * nch + j) << 10) + d;
      c = Fagg[o] * c + Zagg[o];
    }
    h[((size_t)b << 10) + d] = c * sigmoidf_fast(po);
  }
}

// ---------------- MLP: K-split atomic GEMV (ReLU on input) ----------------
// grid (N/64, B, 4 ksplit), block 256 = 64 n x 4 waves
__global__ void mlp_atomic_kernel(const float* __restrict__ in, const float* __restrict__ Wt,
                                  float* __restrict__ out, int K, int N, int relu_in) {
  __shared__ float red[4][64];
  const int nl = threadIdx.x & 63;
  const int w  = threadIdx.x >> 6;
  const int n = blockIdx.x * 64 + nl;
  const int b = blockIdx.y;
  const int k0 = blockIdx.z * (K >> 2) + w * (K >> 4);
  const float* row = in + (size_t)b * K;
  const float* Wc = Wt + n;
  float s = 0.f;
#pragma unroll 8
  for (int k = k0; k < k0 + (K >> 4); ++k) {
    float v = row[k];
    if (relu_in) v = fmaxf(v, 0.f);
    s += v * Wc[(size_t)k * N];
  }
  red[w][nl] = s;
  __syncthreads();
  if (w == 0) {
    s = red[0][nl] + red[1][nl] + red[2][nl] + red[3][nl];
    atomicAdd(&out[(size_t)b * N + n], s);
  }
}

extern "C" void kernel_launch(void* const* d_in, const int* in_sizes, int n_in,
                              void* d_out, int out_size, void* d_ws, size_t ws_size,
                              hipStream_t stream) {
  const float* x  = (const float*)d_in[0];
  const float* W  = (const float*)d_in[1];
  const float* V  = (const float*)d_in[2];
  const float* Vb = (const float*)d_in[3];
  const float* W0 = (const float*)d_in[4];
  const float* b0 = (const float*)d_in[5];
  const float* W1 = (const float*)d_in[6];
  const float* b1 = (const float*)d_in[7];
  const float* W2 = (const float*)d_in[8];
  const float* b2 = (const float*)d_in[9];

  char* ws = (char*)d_ws;
  unsigned short* U = (unsigned short*)(ws);                              // 4 MiB
  float* Fagg = (float*)(ws + (size_t)4 * 1024 * 1024);                   // 2 MiB
  float* Zagg = (float*)(ws + (size_t)6 * 1024 * 1024);                   // 2 MiB
  float* h    = (float*)(ws + (size_t)8 * 1024 * 1024);                   // 128 KiB
  float* q0   = (float*)(ws + (size_t)8 * 1024 * 1024 + 256 * 1024);
  float* q1   = (float*)(ws + (size_t)8 * 1024 * 1024 + 512 * 1024);
  uint4* zpg  = (uint4*)(ws + (size_t)12 * 1024 * 1024);                  // 4 KiB zeros
  unsigned short* xb = (unsigned short*)(ws + (size_t)16 * 1024 * 1024);  // 64 MiB

  const size_t need_bf = (size_t)16 * 1024 * 1024 + (size_t)67108864;
  int use_bf = (ws_size >= need_bf) ? 1 : 0;   // constant across calls -> graph-safe

  prologue_kernel<<<8833, 256, 0, stream>>>(x, W, V, b0, b1, b2, xb, U, q0, q1,
                                            (float*)d_out, zpg);
  if (use_bf) {
    qrnn_main8<<<dim3(8, 8, 32), 512, 0, stream>>>((const unsigned short*)ws, Vb, Fagg, Zagg);
    head_kernel<<<dim3(16, 32), 256, 0, stream>>>(x, W, V, Vb, Fagg, Zagg, h, 8);
  } else {
    qrnn_main<false><<<dim3(16, 16, 32), 256, 0, stream>>>((const unsigned short*)ws, x,
                                                           Vb, Fagg, Zagg);
    head_kernel<<<dim3(16, 32), 256, 0, stream>>>(x, W, V, Vb, Fagg, Zagg, h, 16);
  }
  mlp_atomic_kernel<<<dim3(16, 32, 4), 256, 0, stream>>>(h, W0, q0, 1024, 1024, 0);
  mlp_atomic_kernel<<<dim3(16, 32, 4), 256, 0, stream>>>(q0, W1, q1, 1024, 1024, 1);
  mlp_atomic_kernel<<<dim3(2, 32, 4), 256, 0, stream>>>(q1, W2, (float*)d_out, 1024, 128, 1);
}

// Round 2
// 667.690 us; speedup vs baseline: 1.3626x; 1.3626x over previous
//
#include <hip/hip_runtime.h>
#include <cstdint>
#include <cstddef>

// QRNN fused pipeline for MI355X (gfx950).
// B=32, S=2048, D_in=512, D_model=1024, D_mlp=1024, n_cls=128.
//
// ws layout (bytes): U bf16 [2048][1024] @0 (4MB) | Fagg @4MB | Zagg @6MB |
//   h @8MB | q0 @8MB+256K | q1 @8MB+512K | zero page @12MB (4KB) | xb bf16 @16MB (64MB)
//
// qrnn_main8: 256x256 tile per (b, 256-step chunk, 128 d), 8 waves (2Mx4N),
// BK=32, ring-4 LDS (4 slots x (A 16KB + B 16KB) = 128KB), global_load_lds
// staging 3 K-steps ahead, counted s_waitcnt vmcnt(8) at K-step boundaries
// (never drained in steady state), 2 phases x 16 MFMA per K-step with raw
// s_barrier + s_setprio around each MFMA cluster (T2+T3+T4+T5 stack).
// LDS conflict-freedom: slot swizzle s^=(row>>1)&3 applied on the *global
// source address* (gload_lds dest must stay linear, rule #21) and on reads.
// xprev shift handled structurally: ksteps 0..15 pair x[t] with U k<512 (W),
// ksteps 16..31 pair x[t-1] with U k>=512 (V); t=-1 reads the zero page.
//
// ROUND 2 FIX (rule #20): the scan epilogue's `for (ph)` loop indexed acc with
// the runtime value (ph&1)*4+m -> the WHOLE acc[8][4] array was demoted to
// scratch (VGPR_Count=92, 1.05 GB HBM scratch writeback, MfmaUtil 16.7%).
// The ph loop is now fully unrolled so every acc access is compile-time static.

typedef __attribute__((ext_vector_type(8))) short short8;
typedef __attribute__((ext_vector_type(4))) float f32x4;

#define ZERO_OFF_E 6291456u    // 12MB / 2 (bf16 elements)
#define XB_OFF_E   8388608u    // 16MB / 2
#define U_LDS_BASE 8256        // (old fallback kernel) A stage = 129 rows * 64B

__device__ __forceinline__ unsigned short f2bf(float f) {
  unsigned int u = __float_as_uint(f);
  u += 0x7fffu + ((u >> 16) & 1u);
  return (unsigned short)(u >> 16);
}

__device__ __forceinline__ unsigned stage_addr(int r, int c) {
  return (unsigned)(r * 64 + (((c + r + (r >> 2)) & 3) << 4));
}

__device__ __forceinline__ float sigmoidf_fast(float x) {
  return 1.f / (1.f + __expf(-x));
}
__device__ __forceinline__ float tanhf_fast(float x) {
  float a = fabsf(x);
  float e = __expf(-2.f * a);
  float t = (1.f - e) / (1.f + e);
  return copysignf(t, x);
}

// async 16B global->LDS. LDS dest must be wave-uniform base; lane lands at
// base + lane*16.
__device__ __forceinline__ void gload_lds16(const void* g, const char* lds) {
  __builtin_amdgcn_global_load_lds(
      (const __attribute__((address_space(1))) void*)(uintptr_t)g,
      (__attribute__((address_space(3))) void*)(uint32_t)(uintptr_t)lds, 16, 0, 0);
}

// ---------------- prologue ----------------
// grid 8833: [0,8192) pack_x (4 float4/thread); [8192,8704) pack_u; [8704,8832) init; 8832 zpg
__global__ void prologue_kernel(const float* __restrict__ x, const float* __restrict__ W,
                                const float* __restrict__ V,
                                const float* __restrict__ b0, const float* __restrict__ b1,
                                const float* __restrict__ b2,
                                unsigned short* __restrict__ xb, unsigned short* __restrict__ U,
                                float* __restrict__ q0, float* __restrict__ q1,
                                float* __restrict__ out, uint4* __restrict__ zpg) {
  __shared__ float T[64 * 65];
  const int bx = blockIdx.x;
  if (bx < 8192) {
    int base = bx * 1024 + threadIdx.x;
#pragma unroll
    for (int i = 0; i < 4; ++i) {
      int gid = base + i * 256;
      float4 v = ((const float4*)x)[gid];
      ushort4 o;
      o.x = f2bf(v.x); o.y = f2bf(v.y); o.z = f2bf(v.z); o.w = f2bf(v.w);
      ((ushort4*)xb)[gid] = o;
    }
  } else if (bx < 8704) {
    const int u = bx - 8192;
    const int j0 = (u & 31) * 64;
    const int k0 = (u >> 5) * 64;
    const int jl = threadIdx.x & 63;
    const int q  = threadIdx.x >> 6;
    const float* src = (k0 < 512) ? (W + (size_t)k0 * 3072) : (V + (size_t)(k0 - 512) * 3072);
#pragma unroll 4
    for (int i = 0; i < 16; ++i) {
      int kl = q * 16 + i;
      T[kl * 65 + jl] = src[(size_t)kl * 3072 + j0 + jl];
    }
    __syncthreads();
    const int kl = threadIdx.x & 63;
#pragma unroll 4
    for (int i = 0; i < 16; ++i) {
      int jj = q * 16 + i;
      U[(size_t)(j0 + jj) * 1024 + k0 + kl] = f2bf(T[kl * 65 + jj]);
    }
  } else if (bx < 8832) {
    int gid = (bx - 8704) * 256 + threadIdx.x;   // 32768
    q0[gid] = b0[gid & 1023];
    q1[gid] = b1[gid & 1023];
    if (gid < 4096) out[gid] = b2[gid & 127];
  } else {
    zpg[threadIdx.x] = make_uint4(0u, 0u, 0u, 0u);   // 4 KB zeros
  }
}

// ---------------- main (bf16 path): 256^2 8-wave phase-split pipeline ----------------
// grid (8 dt, 8 cj, 32 b), block 512 (waves: wm=wid>>2 in {0,1} x wn=wid&3 in {0..3})
// per wave: 128 t-rows x 64 cols -> acc[8][4] f32x4.
__global__ __launch_bounds__(512, 2) void qrnn_main8(
    const unsigned short* __restrict__ wsb, const float* __restrict__ Vb,
    float* __restrict__ Fagg, float* __restrict__ Zagg) {
  __shared__ __align__(16) char smem[131072];

  const int dt = blockIdx.x;
  const int cj = blockIdx.y;
  const int b  = blockIdx.z;
  const int tid = threadIdx.x;
  const int lane = tid & 63;
  const int wid  = tid >> 6;
  const int wm = wid >> 2, wn = wid & 3;
  const int l15 = lane & 15, lc = lane >> 4;
  const int s0 = cj * 256;

  f32x4 acc[8][4];
#pragma unroll
  for (int i = 0; i < 8; ++i)
#pragma unroll
    for (int j = 0; j < 4; ++j) acc[i][j] = f32x4{0.f, 0.f, 0.f, 0.f};

  // ---- per-lane staging source offsets (bf16 elements rel. wsb) ----
  // wave w stages A rows [w*32,w*32+32) and B rows same, 2 instr each (16 rows/instr).
  // lane l -> row_g = base + (l>>2), phys slot p = l&3; source uses logical slot
  // q = p ^ ((row_g>>1)&3) so that swizzled reads see linear data (involution).
  unsigned eAx[2], eAp[2], eB[2];
#pragma unroll
  for (int i = 0; i < 2; ++i) {
    int row_g = wid * 32 + i * 16 + (lane >> 2);
    int q = (lane & 3) ^ ((row_g >> 1) & 3);
    int tx = s0 + row_g;                       // ksteps 0..15: x[t]
    eAx[i] = XB_OFF_E + (unsigned)(b * 2048 + tx) * 512u + (unsigned)(q * 8);
    int tp = s0 - 1 + row_g;                   // ksteps 16..31: x[t-1]
    eAp[i] = (tp < 0) ? (ZERO_OFF_E + (unsigned)(q * 8))
                      : (XB_OFF_E + (unsigned)(b * 2048 + tp) * 512u + (unsigned)(q * 8));
    int jj = (row_g < 128) ? (dt * 128 + row_g) : (1024 + dt * 128 + (row_g - 128));
    eB[i] = (unsigned)jj * 1024u + (unsigned)(q * 8);
  }

  // ---- fragment read offsets (swizzle lc ^ ((l15>>1)&3); invariant under mt/nt*16) ----
  const unsigned swz = (unsigned)((lc ^ ((l15 >> 1) & 3)) << 4);
  const unsigned oA = (unsigned)((wm * 128 + l15) * 64) + swz;            // A rows
  const unsigned oB = 16384u + (unsigned)((wn * 64 + l15) * 64) + swz;    // B rows

  auto stage = [&](int kt) {
    const unsigned sbase = (unsigned)((kt & 3) << 15);
    const unsigned kaddB = (unsigned)(kt * 32);
    const unsigned kaddA = (kt < 16) ? kaddB : (unsigned)((kt - 16) * 32);
    const bool xp = (kt < 16);
#pragma unroll
    for (int i = 0; i < 2; ++i) {
      unsigned da = (unsigned)__builtin_amdgcn_readfirstlane(
          (int)(sbase + (unsigned)(wid * 2048 + i * 1024)));
      const unsigned short* src = wsb + ((xp ? eAx[i] : eAp[i]) + kaddA);
      gload_lds16(src, smem + da);
    }
#pragma unroll
    for (int i = 0; i < 2; ++i) {
      unsigned db = (unsigned)__builtin_amdgcn_readfirstlane(
          (int)(sbase + 16384u + (unsigned)(wid * 2048 + i * 1024)));
      const unsigned short* src = wsb + (eB[i] + kaddB);
      gload_lds16(src, smem + db);
    }
  };

  // ---- pipeline prologue: 3 K-steps in flight; wait slot0 (12 issued, keep 8) ----
  stage(0); stage(1); stage(2);
  asm volatile("s_waitcnt vmcnt(8)" ::: "memory");
  __builtin_amdgcn_s_barrier();
  __builtin_amdgcn_sched_barrier(0);

#pragma unroll 1
  for (int kt = 0; kt < 32; ++kt) {
    const char* buf = smem + ((kt & 3) << 15);
    short8 bfr[4], afr[4];
    // ===== phase 0: B-frags + A-frags mt0-3, issue stage(kt+3), 16 MFMA =====
#pragma unroll
    for (int nt = 0; nt < 4; ++nt) bfr[nt] = *(const short8*)(buf + oB + nt * 1024);
#pragma unroll
    for (int m = 0; m < 4; ++m) afr[m] = *(const short8*)(buf + oA + m * 1024);
    if (kt < 29) stage(kt + 3);     // slot (kt+3)&3 == (kt-1)&3: readers done at last boundary
    __builtin_amdgcn_s_barrier();
    __builtin_amdgcn_s_setprio(1);
#pragma unroll
    for (int m = 0; m < 4; ++m)
#pragma unroll
      for (int nt = 0; nt < 4; ++nt)
        acc[m][nt] = __builtin_amdgcn_mfma_f32_16x16x32_bf16(afr[m], bfr[nt], acc[m][nt], 0, 0, 0);
    __builtin_amdgcn_s_setprio(0);
    __builtin_amdgcn_s_barrier();
    // ===== phase 1: A-frags mt4-7, 16 MFMA =====
#pragma unroll
    for (int m = 0; m < 4; ++m) afr[m] = *(const short8*)(buf + oA + (m + 4) * 1024);
    __builtin_amdgcn_s_barrier();
    __builtin_amdgcn_s_setprio(1);
#pragma unroll
    for (int m = 0; m < 4; ++m)
#pragma unroll
      for (int nt = 0; nt < 4; ++nt)
        acc[m + 4][nt] =
            __builtin_amdgcn_mfma_f32_16x16x32_bf16(afr[m], bfr[nt], acc[m + 4][nt], 0, 0, 0);
    __builtin_amdgcn_s_setprio(0);
    // K-step boundary: guarantee slot (kt+1) landed; keep stages kt+2,kt+3 in flight.
    if (kt <= 28)      asm volatile("s_waitcnt vmcnt(8)" ::: "memory");
    else if (kt == 29) asm volatile("s_waitcnt vmcnt(4)" ::: "memory");
    else               asm volatile("s_waitcnt vmcnt(0)" ::: "memory");
    __builtin_amdgcn_s_barrier();
    __builtin_amdgcn_sched_barrier(0);
  }

  // ---- fused activations + scan: 4 phases of 64 timesteps, 128 d ----
  // FULLY UNROLLED over ph: every acc[][] index must be a compile-time constant
  // (rule #20 — runtime-indexed ext_vector arrays get demoted to scratch).
  float* fA   = (float*)smem;                    // [64][132]
  float* tzA  = (float*)(smem + 33792);          // [64][132]
  float* segF = (float*)(smem + 67584);          // [4][128]
  float* segZ = (float*)(smem + 69632);          // [4][128]

  float vb[4];
#pragma unroll
  for (int nt = 0; nt < 4; ++nt)
    vb[nt] = Vb[(wn >> 1) * 1024 + dt * 128 + (wn & 1) * 64 + nt * 16 + l15];

  const int d = tid & 127;
  const int seg = tid >> 7;
  float F_run = 1.f, Z_run = 0.f;

#pragma unroll
  for (int ph = 0; ph < 4; ++ph) {
    __syncthreads();
    if (wm == (ph >> 1)) {
      float* dst = (wn < 2) ? fA : tzA;
#pragma unroll
      for (int m = 0; m < 4; ++m) {
#pragma unroll
        for (int nt = 0; nt < 4; ++nt)
#pragma unroll
          for (int rg = 0; rg < 4; ++rg) {
            int t = m * 16 + (lc << 2) + rg;          // phase-local 0..63
            int c = (wn & 1) * 64 + nt * 16 + l15;    // 0..127
            float v = acc[(ph & 1) * 4 + m][nt][rg] + vb[nt];
            v = (wn < 2) ? sigmoidf_fast(v) : tanhf_fast(v);
            dst[t * 132 + c] = v;
          }
      }
    }
    __syncthreads();
    {
      float F = 1.f, Z = 0.f;
#pragma unroll 4
      for (int i = 0; i < 16; ++i) {
        int t = seg * 16 + i;
        float f  = fA[t * 132 + d];
        float tz = tzA[t * 132 + d];
        float z = (1.f - f) * tz;
        Z = f * Z + z;
        F *= f;
      }
      segF[seg * 128 + d] = F;
      segZ[seg * 128 + d] = Z;
    }
    __syncthreads();
    if (tid < 128) {
#pragma unroll
      for (int sgi = 0; sgi < 4; ++sgi) {
        float Fs = segF[sgi * 128 + tid], Zs = segZ[sgi * 128 + tid];
        Z_run = Fs * Z_run + Zs;
        F_run *= Fs;
      }
    }
  }
  if (tid < 128) {
    size_t o = (((size_t)b * 8 + cj) << 10) + dt * 128 + tid;
    Fagg[o] = F_run;
    Zagg[o] = Z_run;
  }
}

// ---------------- fallback (f32 path, 16-chunk layout) — previous verified kernel ----------------
template <bool USE_BF>
__global__ __launch_bounds__(256, 3) void qrnn_main(
    const unsigned short* __restrict__ wsb, const float* __restrict__ xf,
    const float* __restrict__ Vb,
    float* __restrict__ Fagg, float* __restrict__ Zagg) {
  __shared__ __align__(16) char smem[36864];

  const int dt = blockIdx.x;
  const int cj = blockIdx.y;
  const int b  = blockIdx.z;
  const int tid = threadIdx.x;
  const int lane = tid & 63;
  const int wid  = tid >> 6;
  const int wm = wid >> 1, wn = wid & 1;
  const int s0 = cj * 128;
  const int l15 = lane & 15, lc = lane >> 4;

  f32x4 acc[4][4];
#pragma unroll
  for (int i = 0; i < 4; ++i)
#pragma unroll
    for (int j = 0; j < 4; ++j) acc[i][j] = f32x4{0.f, 0.f, 0.f, 0.f};

  unsigned voffA[2];
  size_t offAF[2]; int zAF[2];
#pragma unroll
  for (int p = 0; p < 2; ++p) {
    int cw = tid + p * 256;
    int r = cw >> 2, c = cw & 3;
    int sg = s0 - 1 + r;
    voffA[p] = (sg < 0) ? (ZERO_OFF_E + (unsigned)(c * 8))
                        : (XB_OFF_E + (unsigned)(b * 2048 + sg) * 512u + (unsigned)(c * 8));
    zAF[p] = (sg < 0);
    offAF[p] = ((size_t)(b * 2048 + (sg < 0 ? 0 : sg)) << 9) + c * 8;
  }
  unsigned voffA3 = XB_OFF_E + (unsigned)(b * 2048 + s0 + 127) * 512u + (unsigned)((tid & 3) * 8);
  size_t offAF3 = ((size_t)(b * 2048 + s0 + 127) << 9) + (tid & 3) * 8;

  unsigned voffU[4];
#pragma unroll
  for (int k = 0; k < 4; ++k) {
    int uw = tid + k * 256;
    int r = uw >> 2, c = uw & 3;
    int col = r & 127, half = r >> 7;
    int j = (col < 64) ? (dt * 64 + col) : (1024 + dt * 64 + (col - 64));
    voffU[k] = (unsigned)(j * 1024 + half * 512 + c * 8);
  }

  unsigned wA[2], wU[4];
#pragma unroll
  for (int p = 0; p < 2; ++p) {
    int cw = tid + p * 256;
    wA[p] = stage_addr(cw >> 2, cw & 3);
  }
  const unsigned wA3 = stage_addr(128, tid & 3);
#pragma unroll
  for (int k = 0; k < 4; ++k) {
    int uw = tid + k * 256;
    wU[k] = U_LDS_BASE + stage_addr(uw >> 2, uw & 3);
  }

  unsigned roA[2][4], roU[2][4];
#pragma unroll
  for (int h2 = 0; h2 < 2; ++h2) {
#pragma unroll
    for (int mt = 0; mt < 4; ++mt) {
      int rr = wm * 64 + l15 + mt * 16 + 1 - h2;
      roA[h2][mt] = stage_addr(rr, lc);
    }
#pragma unroll
    for (int nt = 0; nt < 4; ++nt) {
      int rrU = h2 * 128 + wn * 64 + l15 + nt * 16;
      roU[h2][nt] = U_LDS_BASE + stage_addr(rrU, lc);
    }
  }

  uint4 pA0, pA1, pA3, pU0, pU1, pU2, pU3;

  auto load_stage = [&](int s) {
    const unsigned short* cur = wsb + s * 32;
    if constexpr (USE_BF) {
      pA0 = *(const uint4*)(cur + voffA[0]);
      pA1 = *(const uint4*)(cur + voffA[1]);
      if (tid < 4) pA3 = *(const uint4*)(cur + voffA3);
    } else {
      const float* curf = xf + s * 32;
#pragma unroll
      for (int p = 0; p < 2; ++p) {
        uint4 v = make_uint4(0u, 0u, 0u, 0u);
        if (!zAF[p]) {
          float4 a0 = *(const float4*)(curf + offAF[p]);
          float4 a1 = *(const float4*)(curf + offAF[p] + 4);
          v.x = (unsigned)f2bf(a0.x) | ((unsigned)f2bf(a0.y) << 16);
          v.y = (unsigned)f2bf(a0.z) | ((unsigned)f2bf(a0.w) << 16);
          v.z = (unsigned)f2bf(a1.x) | ((unsigned)f2bf(a1.y) << 16);
          v.w = (unsigned)f2bf(a1.z) | ((unsigned)f2bf(a1.w) << 16);
        }
        if (p == 0) pA0 = v; else pA1 = v;
      }
      if (tid < 4) {
        float4 a0 = *(const float4*)(curf + offAF3);
        float4 a1 = *(const float4*)(curf + offAF3 + 4);
        pA3.x = (unsigned)f2bf(a0.x) | ((unsigned)f2bf(a0.y) << 16);
        pA3.y = (unsigned)f2bf(a0.z) | ((unsigned)f2bf(a0.w) << 16);
        pA3.z = (unsigned)f2bf(a1.x) | ((unsigned)f2bf(a1.y) << 16);
        pA3.w = (unsigned)f2bf(a1.z) | ((unsigned)f2bf(a1.w) << 16);
      }
    }
    pU0 = *(const uint4*)(cur + voffU[0]);
    pU1 = *(const uint4*)(cur + voffU[1]);
    pU2 = *(const uint4*)(cur + voffU[2]);
    pU3 = *(const uint4*)(cur + voffU[3]);
  };

  load_stage(0);

#pragma unroll 1
  for (int s = 0; s < 16; ++s) {
    __syncthreads();
    *(uint4*)(smem + wA[0]) = pA0;
    *(uint4*)(smem + wA[1]) = pA1;
    if (tid < 4) *(uint4*)(smem + wA3) = pA3;
    *(uint4*)(smem + wU[0]) = pU0;
    *(uint4*)(smem + wU[1]) = pU1;
    *(uint4*)(smem + wU[2]) = pU2;
    *(uint4*)(smem + wU[3]) = pU3;
    __syncthreads();
    if (s < 15) load_stage(s + 1);
#pragma unroll
    for (int h2 = 0; h2 < 2; ++h2) {
      short8 bfr[4];
#pragma unroll
      for (int nt = 0; nt < 4; ++nt)
        bfr[nt] = *(const short8*)(smem + roU[h2][nt]);
#pragma unroll
      for (int mt = 0; mt < 4; ++mt) {
        short8 afr = *(const short8*)(smem + roA[h2][mt]);
#pragma unroll
        for (int nt = 0; nt < 4; ++nt)
          acc[mt][nt] = __builtin_amdgcn_mfma_f32_16x16x32_bf16(afr, bfr[nt], acc[mt][nt], 0, 0, 0);
      }
    }
  }

  float* fA   = (float*)smem;
  float* tzA  = (float*)(smem + 17408);
  float* segF = (float*)(smem + 34816);
  float* segZ = (float*)(smem + 35840);

  const int d = tid & 63;
  float vb[4];
#pragma unroll
  for (int nt = 0; nt < 4; ++nt)
    vb[nt] = Vb[wn * 1024 + dt * 64 + nt * 16 + l15];

  float F_run = 1.f, Z_run = 0.f;

  for (int ph = 0; ph < 2; ++ph) {
    __syncthreads();
    if (wm == ph) {
      float* dst = (wn == 0) ? fA : tzA;
#pragma unroll
      for (int mt = 0; mt < 4; ++mt)
#pragma unroll
        for (int nt = 0; nt < 4; ++nt)
#pragma unroll
          for (int rg = 0; rg < 4; ++rg) {
            int t = mt * 16 + ((lane >> 4) << 2) + rg;
            int c = nt * 16 + l15;
            float v = acc[mt][nt][rg] + vb[nt];
            v = (wn == 0) ? sigmoidf_fast(v) : tanhf_fast(v);
            dst[t * 68 + c] = v;
          }
    }
    __syncthreads();
    {
      int seg = tid >> 6;
      float F = 1.f, Z = 0.f;
#pragma unroll 4
      for (int i = 0; i < 16; ++i) {
        int t = seg * 16 + i;
        float f  = fA[t * 68 + d];
        float tz = tzA[t * 68 + d];
        float z = (1.f - f) * tz;
        Z = f * Z + z;
        F *= f;
      }
      segF[seg * 64 + d] = F;
      segZ[seg * 64 + d] = Z;
    }
    __syncthreads();
    if (tid < 64) {
#pragma unroll
      for (int sgi = 0; sgi < 4; ++sgi) {
        float Fs = segF[sgi * 64 + tid], Zs = segZ[sgi * 64 + tid];
        Z_run = Fs * Z_run + Zs;
        F_run *= Fs;
      }
    }
  }
  if (tid < 64) {
    size_t o = (((size_t)b * 16 + cj) << 10) + dt * 64 + tid;
    Fagg[o] = F_run;
    Zagg[o] = Z_run;
  }
}

// ---------------- head: K-split o-gate + nch-chunk combine ----------------
// grid (16 dtile, 32 b), block 256 = 64 d x 4 k-segments
__global__ void head_kernel(const float* __restrict__ x, const float* __restrict__ W,
                            const float* __restrict__ V, const float* __restrict__ Vb,
                            const float* __restrict__ Fagg, const float* __restrict__ Zagg,
                            float* __restrict__ h, int nch) {
  __shared__ float red[4][64];
  const int dl = threadIdx.x & 63;
  const int w  = threadIdx.x >> 6;
  const int d = blockIdx.x * 64 + dl;
  const int b = blockIdx.y;

  const float* xl = x + ((size_t)b * 2048 + 2047) * 512;
  const float* xp = xl - 512;
  const float* Wc = W + 2048 + d;
  const float* Vc = V + 2048 + d;
  float po = 0.f;
  const int k0 = w * 128;
#pragma unroll 8
  for (int k = k0; k < k0 + 128; ++k) {
    po += xl[k] * Wc[(size_t)k * 3072];
    po += xp[k] * Vc[(size_t)k * 3072];
  }
  red[w][dl] = po;
  __syncthreads();
  if (w == 0) {
    po = red[0][dl] + red[1][dl] + red[2][dl] + red[3][dl] + Vb[2048 + d];
    float c = 0.f;
    for (int j = 0; j < nch; ++j) {
      size_t o = (((size_t)b * nch + j) << 10) + d;
      c = Fagg[o] * c + Zagg[o];
    }
    h[((size_t)b << 10) + d] = c * sigmoidf_fast(po);
  }
}

// ---------------- MLP: K-split atomic GEMV (ReLU on input) ----------------
// grid (N/64, B, 4 ksplit), block 256 = 64 n x 4 waves
__global__ void mlp_atomic_kernel(const float* __restrict__ in, const float* __restrict__ Wt,
                                  float* __restrict__ out, int K, int N, int relu_in) {
  __shared__ float red[4][64];
  const int nl = threadIdx.x & 63;
  const int w  = threadIdx.x >> 6;
  const int n = blockIdx.x * 64 + nl;
  const int b = blockIdx.y;
  const int k0 = blockIdx.z * (K >> 2) + w * (K >> 4);
  const float* row = in + (size_t)b * K;
  const float* Wc = Wt + n;
  float s = 0.f;
#pragma unroll 8
  for (int k = k0; k < k0 + (K >> 4); ++k) {
    float v = row[k];
    if (relu_in) v = fmaxf(v, 0.f);
    s += v * Wc[(size_t)k * N];
  }
  red[w][nl] = s;
  __syncthreads();
  if (w == 0) {
    s = red[0][nl] + red[1][nl] + red[2][nl] + red[3][nl];
    atomicAdd(&out[(size_t)b * N + n], s);
  }
}

extern "C" void kernel_launch(void* const* d_in, const int* in_sizes, int n_in,
                              void* d_out, int out_size, void* d_ws, size_t ws_size,
                              hipStream_t stream) {
  const float* x  = (const float*)d_in[0];
  const float* W  = (const float*)d_in[1];
  const float* V  = (const float*)d_in[2];
  const float* Vb = (const float*)d_in[3];
  const float* W0 = (const float*)d_in[4];
  const float* b0 = (const float*)d_in[5];
  const float* W1 = (const float*)d_in[6];
  const float* b1 = (const float*)d_in[7];
  const float* W2 = (const float*)d_in[8];
  const float* b2 = (const float*)d_in[9];

  char* ws = (char*)d_ws;
  unsigned short* U = (unsigned short*)(ws);                              // 4 MiB
  float* Fagg = (float*)(ws + (size_t)4 * 1024 * 1024);                   // 2 MiB
  float* Zagg = (float*)(ws + (size_t)6 * 1024 * 1024);                   // 2 MiB
  float* h    = (float*)(ws + (size_t)8 * 1024 * 1024);                   // 128 KiB
  float* q0   = (float*)(ws + (size_t)8 * 1024 * 1024 + 256 * 1024);
  float* q1   = (float*)(ws + (size_t)8 * 1024 * 1024 + 512 * 1024);
  uint4* zpg  = (uint4*)(ws + (size_t)12 * 1024 * 1024);                  // 4 KiB zeros
  unsigned short* xb = (unsigned short*)(ws + (size_t)16 * 1024 * 1024);  // 64 MiB

  const size_t need_bf = (size_t)16 * 1024 * 1024 + (size_t)67108864;
  int use_bf = (ws_size >= need_bf) ? 1 : 0;   // constant across calls -> graph-safe

  prologue_kernel<<<8833, 256, 0, stream>>>(x, W, V, b0, b1, b2, xb, U, q0, q1,
                                            (float*)d_out, zpg);
  if (use_bf) {
    qrnn_main8<<<dim3(8, 8, 32), 512, 0, stream>>>((const unsigned short*)ws, Vb, Fagg, Zagg);
    head_kernel<<<dim3(16, 32), 256, 0, stream>>>(x, W, V, Vb, Fagg, Zagg, h, 8);
  } else {
    qrnn_main<false><<<dim3(16, 16, 32), 256, 0, stream>>>((const unsigned short*)ws, x,
                                                           Vb, Fagg, Zagg);
    head_kernel<<<dim3(16, 32), 256, 0, stream>>>(x, W, V, Vb, Fagg, Zagg, h, 16);
  }
  mlp_atomic_kernel<<<dim3(16, 32, 4), 256, 0, stream>>>(h, W0, q0, 1024, 1024, 0);
  mlp_atomic_kernel<<<dim3(16, 32, 4), 256, 0, stream>>>(q0, W1, q1, 1024, 1024, 1);
  mlp_atomic_kernel<<<dim3(2, 32, 4), 256, 0, stream>>>(q1, W2, (float*)d_out, 1024, 128, 1);
}

// Round 3
// 666.856 us; speedup vs baseline: 1.3643x; 1.0013x over previous
//
#include <hip/hip_runtime.h>
#include <cstdint>
#include <cstddef>

// QRNN fused pipeline for MI355X (gfx950).
// B=32, S=2048, D_in=512, D_model=1024, D_mlp=1024, n_cls=128.
//
// ws layout (bytes): U bf16 [2048][1024] @0 (4MB) | Fagg @4MB | Zagg @6MB |
//   h @8MB | q0 @8MB+256K | q1 @8MB+512K | zero page @12MB (4KB) | xb bf16 @16MB (64MB)
//
// qrnn_main8 (round 3): 256x256 tile, 8 waves, BK=32, ring-4 LDS, depth-3
// global_load_lds staging, m201-style one-phase-ahead register pipeline:
//   phase A: read afrH(slot kt) | 2 gloads | bar | 16 MFMA low | 2 gloads |
//            vmcnt(8) | bar
//   phase B: read bfr/afrL(slot kt+1) | bar | 16 MFMA high | bar
// Ping-pong register sets via unroll-by-2 (rule #20: all indices static).
// XCD-chunked block swizzle: 1D grid 2048, orig=(bid&7)*256+(bid>>3) so the
// 8 dt-blocks sharing an A-panel run consecutively on ONE XCD (T1).
//
// Round-2 lesson kept: scan epilogue ph-loop fully unrolled (acc static idx).

typedef __attribute__((ext_vector_type(8))) short short8;
typedef __attribute__((ext_vector_type(4))) float f32x4;

#define ZERO_OFF_E 6291456u    // 12MB / 2 (bf16 elements)
#define XB_OFF_E   8388608u    // 16MB / 2
#define U_LDS_BASE 8256        // (old fallback kernel) A stage = 129 rows * 64B

__device__ __forceinline__ unsigned short f2bf(float f) {
  unsigned int u = __float_as_uint(f);
  u += 0x7fffu + ((u >> 16) & 1u);
  return (unsigned short)(u >> 16);
}

__device__ __forceinline__ unsigned stage_addr(int r, int c) {
  return (unsigned)(r * 64 + (((c + r + (r >> 2)) & 3) << 4));
}

__device__ __forceinline__ float sigmoidf_fast(float x) {
  return 1.f / (1.f + __expf(-x));
}
__device__ __forceinline__ float tanhf_fast(float x) {
  float a = fabsf(x);
  float e = __expf(-2.f * a);
  float t = (1.f - e) / (1.f + e);
  return copysignf(t, x);
}

// async 16B global->LDS. LDS dest must be wave-uniform base; lane lands at
// base + lane*16.
__device__ __forceinline__ void gload_lds16(const void* g, const char* lds) {
  __builtin_amdgcn_global_load_lds(
      (const __attribute__((address_space(1))) void*)(uintptr_t)g,
      (__attribute__((address_space(3))) void*)(uint32_t)(uintptr_t)lds, 16, 0, 0);
}

// ---------------- prologue ----------------
// grid 8833: [0,8192) pack_x (4 float4/thread); [8192,8704) pack_u; [8704,8832) init; 8832 zpg
__global__ void prologue_kernel(const float* __restrict__ x, const float* __restrict__ W,
                                const float* __restrict__ V,
                                const float* __restrict__ b0, const float* __restrict__ b1,
                                const float* __restrict__ b2,
                                unsigned short* __restrict__ xb, unsigned short* __restrict__ U,
                                float* __restrict__ q0, float* __restrict__ q1,
                                float* __restrict__ out, uint4* __restrict__ zpg) {
  __shared__ float T[64 * 65];
  const int bx = blockIdx.x;
  if (bx < 8192) {
    int base = bx * 1024 + threadIdx.x;
#pragma unroll
    for (int i = 0; i < 4; ++i) {
      int gid = base + i * 256;
      float4 v = ((const float4*)x)[gid];
      ushort4 o;
      o.x = f2bf(v.x); o.y = f2bf(v.y); o.z = f2bf(v.z); o.w = f2bf(v.w);
      ((ushort4*)xb)[gid] = o;
    }
  } else if (bx < 8704) {
    const int u = bx - 8192;
    const int j0 = (u & 31) * 64;
    const int k0 = (u >> 5) * 64;
    const int jl = threadIdx.x & 63;
    const int q  = threadIdx.x >> 6;
    const float* src = (k0 < 512) ? (W + (size_t)k0 * 3072) : (V + (size_t)(k0 - 512) * 3072);
#pragma unroll 4
    for (int i = 0; i < 16; ++i) {
      int kl = q * 16 + i;
      T[kl * 65 + jl] = src[(size_t)kl * 3072 + j0 + jl];
    }
    __syncthreads();
    const int kl = threadIdx.x & 63;
#pragma unroll 4
    for (int i = 0; i < 16; ++i) {
      int jj = q * 16 + i;
      U[(size_t)(j0 + jj) * 1024 + k0 + kl] = f2bf(T[kl * 65 + jj]);
    }
  } else if (bx < 8832) {
    int gid = (bx - 8704) * 256 + threadIdx.x;   // 32768
    q0[gid] = b0[gid & 1023];
    q1[gid] = b1[gid & 1023];
    if (gid < 4096) out[gid] = b2[gid & 127];
  } else {
    zpg[threadIdx.x] = make_uint4(0u, 0u, 0u, 0u);   // 4 KB zeros
  }
}

// ---------------- main (bf16 path): 256^2 8-wave m201-style pipeline ----------------
// grid 2048 (1D, XCD-chunked), block 512 (waves: wm=wid>>2 x wn=wid&3)
// per wave: 128 t-rows x 64 cols -> acc[8][4] f32x4.
__global__ __launch_bounds__(512, 2) void qrnn_main8(
    const unsigned short* __restrict__ wsb, const float* __restrict__ Vb,
    float* __restrict__ Fagg, float* __restrict__ Zagg) {
  __shared__ __align__(16) char smem[131072];

  // XCD-chunked swizzle: nwg=2048, nwg%8==0 -> bijective. Blocks with the same
  // (b,cj) A-panel (consecutive orig, dt fastest) land on the SAME XCD.
  const int bid  = blockIdx.x;
  const int orig = (bid & 7) * 256 + (bid >> 3);
  const int dt = orig & 7;
  const int cj = (orig >> 3) & 7;
  const int b  = orig >> 6;

  const int tid = threadIdx.x;
  const int lane = tid & 63;
  const int wid  = tid >> 6;
  const int wm = wid >> 2, wn = wid & 3;
  const int l15 = lane & 15, lc = lane >> 4;
  const int s0 = cj * 256;

  f32x4 acc[8][4];
#pragma unroll
  for (int i = 0; i < 8; ++i)
#pragma unroll
    for (int j = 0; j < 4; ++j) acc[i][j] = f32x4{0.f, 0.f, 0.f, 0.f};

  // ---- per-lane staging source offsets (bf16 elements rel. wsb) ----
  unsigned eAx[2], eAp[2], eB[2];
#pragma unroll
  for (int i = 0; i < 2; ++i) {
    int row_g = wid * 32 + i * 16 + (lane >> 2);
    int q = (lane & 3) ^ ((row_g >> 1) & 3);
    int tx = s0 + row_g;                       // ksteps 0..15: x[t]
    eAx[i] = XB_OFF_E + (unsigned)(b * 2048 + tx) * 512u + (unsigned)(q * 8);
    int tp = s0 - 1 + row_g;                   // ksteps 16..31: x[t-1]
    eAp[i] = (tp < 0) ? (ZERO_OFF_E + (unsigned)(q * 8))
                      : (XB_OFF_E + (unsigned)(b * 2048 + tp) * 512u + (unsigned)(q * 8));
    int jj = (row_g < 128) ? (dt * 128 + row_g) : (1024 + dt * 128 + (row_g - 128));
    eB[i] = (unsigned)jj * 1024u + (unsigned)(q * 8);
  }

  // ---- fragment read offsets (swizzle lc ^ ((l15>>1)&3)) ----
  const unsigned swz = (unsigned)((lc ^ ((l15 >> 1) & 3)) << 4);
  const unsigned oA = (unsigned)((wm * 128 + l15) * 64) + swz;            // A rows
  const unsigned oB = 16384u + (unsigned)((wn * 64 + l15) * 64) + swz;    // B rows

  auto stage_half = [&](int kt, int h) {
    const unsigned sbase = (unsigned)((kt & 3) << 15);
    if (h == 0) {
      const unsigned kaddA = (kt < 16) ? (unsigned)(kt * 32) : (unsigned)((kt - 16) * 32);
      const bool xp = (kt < 16);
#pragma unroll
      for (int i = 0; i < 2; ++i) {
        unsigned da = (unsigned)__builtin_amdgcn_readfirstlane(
            (int)(sbase + (unsigned)(wid * 2048 + i * 1024)));
        gload_lds16(wsb + ((xp ? eAx[i] : eAp[i]) + kaddA), smem + da);
      }
    } else {
      const unsigned kaddB = (unsigned)(kt * 32);
#pragma unroll
      for (int i = 0; i < 2; ++i) {
        unsigned db = (unsigned)__builtin_amdgcn_readfirstlane(
            (int)(sbase + 16384u + (unsigned)(wid * 2048 + i * 1024)));
        gload_lds16(wsb + (eB[i] + kaddB), smem + db);
      }
    }
  };

  // ---- pipeline prologue: slots 0..2 in flight; wait slot0 (12 issued, keep 8) ----
  stage_half(0, 0); stage_half(0, 1);
  stage_half(1, 0); stage_half(1, 1);
  stage_half(2, 0); stage_half(2, 1);
  asm volatile("s_waitcnt vmcnt(8)" ::: "memory");
  __builtin_amdgcn_s_barrier();
  __builtin_amdgcn_sched_barrier(0);

  short8 bC[4], aC[4], bN[4], aN[4], aH[4];
  // preload kt=0 low-half operands from slot 0
#pragma unroll
  for (int nt = 0; nt < 4; ++nt) bC[nt] = *(const short8*)(smem + oB + nt * 1024);
#pragma unroll
  for (int m = 0; m < 4; ++m)   aC[m]  = *(const short8*)(smem + oA + m * 1024);

  // One K-step. Bc/Ac: operands for THIS kstep (already in regs).
  // Bn/An: filled during phase B with NEXT kstep's operands (from slot kt+1).
#define KSTEP(KT, Bc, Ac, Bn, An)                                                   \
  {                                                                                 \
    const int kt = (KT);                                                            \
    const char* buf  = smem + ((kt & 3) << 15);                                     \
    const char* bufn = smem + (((kt + 1) & 3) << 15);                               \
    /* phase A: high-half A frags (this slot) + first staging half */               \
    _Pragma("unroll")                                                               \
    for (int m = 0; m < 4; ++m) aH[m] = *(const short8*)(buf + oA + (m + 4) * 1024);\
    if (kt < 29) stage_half(kt + 3, 0);                                             \
    __builtin_amdgcn_s_barrier();                                                   \
    __builtin_amdgcn_s_setprio(1);                                                  \
    _Pragma("unroll")                                                               \
    for (int m = 0; m < 4; ++m)                                                     \
      _Pragma("unroll")                                                             \
      for (int nt = 0; nt < 4; ++nt)                                                \
        acc[m][nt] =                                                                \
            __builtin_amdgcn_mfma_f32_16x16x32_bf16(Ac[m], Bc[nt], acc[m][nt], 0, 0, 0); \
    __builtin_amdgcn_s_setprio(0);                                                  \
    if (kt < 29) stage_half(kt + 3, 1);                                             \
    if (kt <= 28)      asm volatile("s_waitcnt vmcnt(8)" ::: "memory");             \
    else if (kt == 29) asm volatile("s_waitcnt vmcnt(4)" ::: "memory");             \
    else if (kt == 30) asm volatile("s_waitcnt vmcnt(0)" ::: "memory");             \
    __builtin_amdgcn_s_barrier();                                                   \
    /* phase B: next kstep's low-half operands from slot kt+1 */                    \
    if (kt < 31) {                                                                  \
      _Pragma("unroll")                                                             \
      for (int nt = 0; nt < 4; ++nt) Bn[nt] = *(const short8*)(bufn + oB + nt * 1024); \
      _Pragma("unroll")                                                             \
      for (int m = 0; m < 4; ++m)   An[m]  = *(const short8*)(bufn + oA + m * 1024);\
    }                                                                               \
    __builtin_amdgcn_s_barrier();                                                   \
    __builtin_amdgcn_s_setprio(1);                                                  \
    _Pragma("unroll")                                                               \
    for (int m = 0; m < 4; ++m)                                                     \
      _Pragma("unroll")                                                             \
      for (int nt = 0; nt < 4; ++nt)                                                \
        acc[m + 4][nt] =                                                            \
            __builtin_amdgcn_mfma_f32_16x16x32_bf16(aH[m], Bc[nt], acc[m + 4][nt], 0, 0, 0); \
    __builtin_amdgcn_s_setprio(0);                                                  \
    __builtin_amdgcn_s_barrier();                                                   \
    __builtin_amdgcn_sched_barrier(0);                                              \
  }

#pragma unroll 1
  for (int k2 = 0; k2 < 32; k2 += 2) {
    KSTEP(k2,     bC, aC, bN, aN);
    KSTEP(k2 + 1, bN, aN, bC, aC);
  }
#undef KSTEP

  // ---- fused activations + scan: 4 phases of 64 timesteps, 128 d ----
  // ph fully unrolled (rule #20: acc indices must be compile-time constants).
  float* fA   = (float*)smem;                    // [64][132]
  float* tzA  = (float*)(smem + 33792);          // [64][132]
  float* segF = (float*)(smem + 67584);          // [4][128]
  float* segZ = (float*)(smem + 69632);          // [4][128]

  float vb[4];
#pragma unroll
  for (int nt = 0; nt < 4; ++nt)
    vb[nt] = Vb[(wn >> 1) * 1024 + dt * 128 + (wn & 1) * 64 + nt * 16 + l15];

  const int d = tid & 127;
  const int seg = tid >> 7;
  float F_run = 1.f, Z_run = 0.f;

#pragma unroll
  for (int ph = 0; ph < 4; ++ph) {
    __syncthreads();
    if (wm == (ph >> 1)) {
      float* dst = (wn < 2) ? fA : tzA;
#pragma unroll
      for (int m = 0; m < 4; ++m) {
#pragma unroll
        for (int nt = 0; nt < 4; ++nt)
#pragma unroll
          for (int rg = 0; rg < 4; ++rg) {
            int t = m * 16 + (lc << 2) + rg;          // phase-local 0..63
            int c = (wn & 1) * 64 + nt * 16 + l15;    // 0..127
            float v = acc[(ph & 1) * 4 + m][nt][rg] + vb[nt];
            v = (wn < 2) ? sigmoidf_fast(v) : tanhf_fast(v);
            dst[t * 132 + c] = v;
          }
      }
    }
    __syncthreads();
    {
      float F = 1.f, Z = 0.f;
#pragma unroll 4
      for (int i = 0; i < 16; ++i) {
        int t = seg * 16 + i;
        float f  = fA[t * 132 + d];
        float tz = tzA[t * 132 + d];
        float z = (1.f - f) * tz;
        Z = f * Z + z;
        F *= f;
      }
      segF[seg * 128 + d] = F;
      segZ[seg * 128 + d] = Z;
    }
    __syncthreads();
    if (tid < 128) {
#pragma unroll
      for (int sgi = 0; sgi < 4; ++sgi) {
        float Fs = segF[sgi * 128 + tid], Zs = segZ[sgi * 128 + tid];
        Z_run = Fs * Z_run + Zs;
        F_run *= Fs;
      }
    }
  }
  if (tid < 128) {
    size_t o = (((size_t)b * 8 + cj) << 10) + dt * 128 + tid;
    Fagg[o] = F_run;
    Zagg[o] = Z_run;
  }
}

// ---------------- fallback (f32 path, 16-chunk layout) — previous verified kernel ----------------
template <bool USE_BF>
__global__ __launch_bounds__(256, 3) void qrnn_main(
    const unsigned short* __restrict__ wsb, const float* __restrict__ xf,
    const float* __restrict__ Vb,
    float* __restrict__ Fagg, float* __restrict__ Zagg) {
  __shared__ __align__(16) char smem[36864];

  const int dt = blockIdx.x;
  const int cj = blockIdx.y;
  const int b  = blockIdx.z;
  const int tid = threadIdx.x;
  const int lane = tid & 63;
  const int wid  = tid >> 6;
  const int wm = wid >> 1, wn = wid & 1;
  const int s0 = cj * 128;
  const int l15 = lane & 15, lc = lane >> 4;

  f32x4 acc[4][4];
#pragma unroll
  for (int i = 0; i < 4; ++i)
#pragma unroll
    for (int j = 0; j < 4; ++j) acc[i][j] = f32x4{0.f, 0.f, 0.f, 0.f};

  unsigned voffA[2];
  size_t offAF[2]; int zAF[2];
#pragma unroll
  for (int p = 0; p < 2; ++p) {
    int cw = tid + p * 256;
    int r = cw >> 2, c = cw & 3;
    int sg = s0 - 1 + r;
    voffA[p] = (sg < 0) ? (ZERO_OFF_E + (unsigned)(c * 8))
                        : (XB_OFF_E + (unsigned)(b * 2048 + sg) * 512u + (unsigned)(c * 8));
    zAF[p] = (sg < 0);
    offAF[p] = ((size_t)(b * 2048 + (sg < 0 ? 0 : sg)) << 9) + c * 8;
  }
  unsigned voffA3 = XB_OFF_E + (unsigned)(b * 2048 + s0 + 127) * 512u + (unsigned)((tid & 3) * 8);
  size_t offAF3 = ((size_t)(b * 2048 + s0 + 127) << 9) + (tid & 3) * 8;

  unsigned voffU[4];
#pragma unroll
  for (int k = 0; k < 4; ++k) {
    int uw = tid + k * 256;
    int r = uw >> 2, c = uw & 3;
    int col = r & 127, half = r >> 7;
    int j = (col < 64) ? (dt * 64 + col) : (1024 + dt * 64 + (col - 64));
    voffU[k] = (unsigned)(j * 1024 + half * 512 + c * 8);
  }

  unsigned wA[2], wU[4];
#pragma unroll
  for (int p = 0; p < 2; ++p) {
    int cw = tid + p * 256;
    wA[p] = stage_addr(cw >> 2, cw & 3);
  }
  const unsigned wA3 = stage_addr(128, tid & 3);
#pragma unroll
  for (int k = 0; k < 4; ++k) {
    int uw = tid + k * 256;
    wU[k] = U_LDS_BASE + stage_addr(uw >> 2, uw & 3);
  }

  unsigned roA[2][4], roU[2][4];
#pragma unroll
  for (int h2 = 0; h2 < 2; ++h2) {
#pragma unroll
    for (int mt = 0; mt < 4; ++mt) {
      int rr = wm * 64 + l15 + mt * 16 + 1 - h2;
      roA[h2][mt] = stage_addr(rr, lc);
    }
#pragma unroll
    for (int nt = 0; nt < 4; ++nt) {
      int rrU = h2 * 128 + wn * 64 + l15 + nt * 16;
      roU[h2][nt] = U_LDS_BASE + stage_addr(rrU, lc);
    }
  }

  uint4 pA0, pA1, pA3, pU0, pU1, pU2, pU3;

  auto load_stage = [&](int s) {
    const unsigned short* cur = wsb + s * 32;
    if constexpr (USE_BF) {
      pA0 = *(const uint4*)(cur + voffA[0]);
      pA1 = *(const uint4*)(cur + voffA[1]);
      if (tid < 4) pA3 = *(const uint4*)(cur + voffA3);
    } else {
      const float* curf = xf + s * 32;
#pragma unroll
      for (int p = 0; p < 2; ++p) {
        uint4 v = make_uint4(0u, 0u, 0u, 0u);
        if (!zAF[p]) {
          float4 a0 = *(const float4*)(curf + offAF[p]);
          float4 a1 = *(const float4*)(curf + offAF[p] + 4);
          v.x = (unsigned)f2bf(a0.x) | ((unsigned)f2bf(a0.y) << 16);
          v.y = (unsigned)f2bf(a0.z) | ((unsigned)f2bf(a0.w) << 16);
          v.z = (unsigned)f2bf(a1.x) | ((unsigned)f2bf(a1.y) << 16);
          v.w = (unsigned)f2bf(a1.z) | ((unsigned)f2bf(a1.w) << 16);
        }
        if (p == 0) pA0 = v; else pA1 = v;
      }
      if (tid < 4) {
        float4 a0 = *(const float4*)(curf + offAF3);
        float4 a1 = *(const float4*)(curf + offAF3 + 4);
        pA3.x = (unsigned)f2bf(a0.x) | ((unsigned)f2bf(a0.y) << 16);
        pA3.y = (unsigned)f2bf(a0.z) | ((unsigned)f2bf(a0.w) << 16);
        pA3.z = (unsigned)f2bf(a1.x) | ((unsigned)f2bf(a1.y) << 16);
        pA3.w = (unsigned)f2bf(a1.z) | ((unsigned)f2bf(a1.w) << 16);
      }
    }
    pU0 = *(const uint4*)(cur + voffU[0]);
    pU1 = *(const uint4*)(cur + voffU[1]);
    pU2 = *(const uint4*)(cur + voffU[2]);
    pU3 = *(const uint4*)(cur + voffU[3]);
  };

  load_stage(0);

#pragma unroll 1
  for (int s = 0; s < 16; ++s) {
    __syncthreads();
    *(uint4*)(smem + wA[0]) = pA0;
    *(uint4*)(smem + wA[1]) = pA1;
    if (tid < 4) *(uint4*)(smem + wA3) = pA3;
    *(uint4*)(smem + wU[0]) = pU0;
    *(uint4*)(smem + wU[1]) = pU1;
    *(uint4*)(smem + wU[2]) = pU2;
    *(uint4*)(smem + wU[3]) = pU3;
    __syncthreads();
    if (s < 15) load_stage(s + 1);
#pragma unroll
    for (int h2 = 0; h2 < 2; ++h2) {
      short8 bfr[4];
#pragma unroll
      for (int nt = 0; nt < 4; ++nt)
        bfr[nt] = *(const short8*)(smem + roU[h2][nt]);
#pragma unroll
      for (int mt = 0; mt < 4; ++mt) {
        short8 afr = *(const short8*)(smem + roA[h2][mt]);
#pragma unroll
        for (int nt = 0; nt < 4; ++nt)
          acc[mt][nt] = __builtin_amdgcn_mfma_f32_16x16x32_bf16(afr, bfr[nt], acc[mt][nt], 0, 0, 0);
      }
    }
  }

  float* fA   = (float*)smem;
  float* tzA  = (float*)(smem + 17408);
  float* segF = (float*)(smem + 34816);
  float* segZ = (float*)(smem + 35840);

  const int d = tid & 63;
  float vb[4];
#pragma unroll
  for (int nt = 0; nt < 4; ++nt)
    vb[nt] = Vb[wn * 1024 + dt * 64 + nt * 16 + l15];

  float F_run = 1.f, Z_run = 0.f;

  for (int ph = 0; ph < 2; ++ph) {
    __syncthreads();
    if (wm == ph) {
      float* dst = (wn == 0) ? fA : tzA;
#pragma unroll
      for (int mt = 0; mt < 4; ++mt)
#pragma unroll
        for (int nt = 0; nt < 4; ++nt)
#pragma unroll
          for (int rg = 0; rg < 4; ++rg) {
            int t = mt * 16 + ((lane >> 4) << 2) + rg;
            int c = nt * 16 + l15;
            float v = acc[mt][nt][rg] + vb[nt];
            v = (wn == 0) ? sigmoidf_fast(v) : tanhf_fast(v);
            dst[t * 68 + c] = v;
          }
    }
    __syncthreads();
    {
      int seg = tid >> 6;
      float F = 1.f, Z = 0.f;
#pragma unroll 4
      for (int i = 0; i < 16; ++i) {
        int t = seg * 16 + i;
        float f  = fA[t * 68 + d];
        float tz = tzA[t * 68 + d];
        float z = (1.f - f) * tz;
        Z = f * Z + z;
        F *= f;
      }
      segF[seg * 64 + d] = F;
      segZ[seg * 64 + d] = Z;
    }
    __syncthreads();
    if (tid < 64) {
#pragma unroll
      for (int sgi = 0; sgi < 4; ++sgi) {
        float Fs = segF[sgi * 64 + tid], Zs = segZ[sgi * 64 + tid];
        Z_run = Fs * Z_run + Zs;
        F_run *= Fs;
      }
    }
  }
  if (tid < 64) {
    size_t o = (((size_t)b * 16 + cj) << 10) + dt * 64 + tid;
    Fagg[o] = F_run;
    Zagg[o] = Z_run;
  }
}

// ---------------- head: K-split o-gate + nch-chunk combine ----------------
// grid (16 dtile, 32 b), block 256 = 64 d x 4 k-segments
__global__ void head_kernel(const float* __restrict__ x, const float* __restrict__ W,
                            const float* __restrict__ V, const float* __restrict__ Vb,
                            const float* __restrict__ Fagg, const float* __restrict__ Zagg,
                            float* __restrict__ h, int nch) {
  __shared__ float red[4][64];
  const int dl = threadIdx.x & 63;
  const int w  = threadIdx.x >> 6;
  const int d = blockIdx.x * 64 + dl;
  const int b = blockIdx.y;

  const float* xl = x + ((size_t)b * 2048 + 2047) * 512;
  const float* xp = xl - 512;
  const float* Wc = W + 2048 + d;
  const float* Vc = V + 2048 + d;
  float po = 0.f;
  const int k0 = w * 128;
#pragma unroll 8
  for (int k = k0; k < k0 + 128; ++k) {
    po += xl[k] * Wc[(size_t)k * 3072];
    po += xp[k] * Vc[(size_t)k * 3072];
  }
  red[w][dl] = po;
  __syncthreads();
  if (w == 0) {
    po = red[0][dl] + red[1][dl] + red[2][dl] + red[3][dl] + Vb[2048 + d];
    float c = 0.f;
    for (int j = 0; j < nch; ++j) {
      size_t o = (((size_t)b * nch + j) << 10) + d;
      c = Fagg[o] * c + Zagg[o];
    }
    h[((size_t)b << 10) + d] = c * sigmoidf_fast(po);
  }
}

// ---------------- MLP: K-split atomic GEMV (ReLU on input) ----------------
// grid (N/64, B, 4 ksplit), block 256 = 64 n x 4 waves
__global__ void mlp_atomic_kernel(const float* __restrict__ in, const float* __restrict__ Wt,
                                  float* __restrict__ out, int K, int N, int relu_in) {
  __shared__ float red[4][64];
  const int nl = threadIdx.x & 63;
  const int w  = threadIdx.x >> 6;
  const int n = blockIdx.x * 64 + nl;
  const int b = blockIdx.y;
  const int k0 = blockIdx.z * (K >> 2) + w * (K >> 4);
  const float* row = in + (size_t)b * K;
  const float* Wc = Wt + n;
  float s = 0.f;
#pragma unroll 8
  for (int k = k0; k < k0 + (K >> 4); ++k) {
    float v = row[k];
    if (relu_in) v = fmaxf(v, 0.f);
    s += v * Wc[(size_t)k * N];
  }
  red[w][nl] = s;
  __syncthreads();
  if (w == 0) {
    s = red[0][nl] + red[1][nl] + red[2][nl] + red[3][nl];
    atomicAdd(&out[(size_t)b * N + n], s);
  }
}

extern "C" void kernel_launch(void* const* d_in, const int* in_sizes, int n_in,
                              void* d_out, int out_size, void* d_ws, size_t ws_size,
                              hipStream_t stream) {
  const float* x  = (const float*)d_in[0];
  const float* W  = (const float*)d_in[1];
  const float* V  = (const float*)d_in[2];
  const float* Vb = (const float*)d_in[3];
  const float* W0 = (const float*)d_in[4];
  const float* b0 = (const float*)d_in[5];
  const float* W1 = (const float*)d_in[6];
  const float* b1 = (const float*)d_in[7];
  const float* W2 = (const float*)d_in[8];
  const float* b2 = (const float*)d_in[9];

  char* ws = (char*)d_ws;
  unsigned short* U = (unsigned short*)(ws);                              // 4 MiB
  float* Fagg = (float*)(ws + (size_t)4 * 1024 * 1024);                   // 2 MiB
  float* Zagg = (float*)(ws + (size_t)6 * 1024 * 1024);                   // 2 MiB
  float* h    = (float*)(ws + (size_t)8 * 1024 * 1024);                   // 128 KiB
  float* q0   = (float*)(ws + (size_t)8 * 1024 * 1024 + 256 * 1024);
  float* q1   = (float*)(ws + (size_t)8 * 1024 * 1024 + 512 * 1024);
  uint4* zpg  = (uint4*)(ws + (size_t)12 * 1024 * 1024);                  // 4 KiB zeros
  unsigned short* xb = (unsigned short*)(ws + (size_t)16 * 1024 * 1024);  // 64 MiB

  const size_t need_bf = (size_t)16 * 1024 * 1024 + (size_t)67108864;
  int use_bf = (ws_size >= need_bf) ? 1 : 0;   // constant across calls -> graph-safe

  prologue_kernel<<<8833, 256, 0, stream>>>(x, W, V, b0, b1, b2, xb, U, q0, q1,
                                            (float*)d_out, zpg);
  if (use_bf) {
    qrnn_main8<<<2048, 512, 0, stream>>>((const unsigned short*)ws, Vb, Fagg, Zagg);
    head_kernel<<<dim3(16, 32), 256, 0, stream>>>(x, W, V, Vb, Fagg, Zagg, h, 8);
  } else {
    qrnn_main<false><<<dim3(16, 16, 32), 256, 0, stream>>>((const unsigned short*)ws, x,
                                                           Vb, Fagg, Zagg);
    head_kernel<<<dim3(16, 32), 256, 0, stream>>>(x, W, V, Vb, Fagg, Zagg, h, 16);
  }
  mlp_atomic_kernel<<<dim3(16, 32, 4), 256, 0, stream>>>(h, W0, q0, 1024, 1024, 0);
  mlp_atomic_kernel<<<dim3(16, 32, 4), 256, 0, stream>>>(q0, W1, q1, 1024, 1024, 1);
  mlp_atomic_kernel<<<dim3(2, 32, 4), 256, 0, stream>>>(q1, W2, (float*)d_out, 1024, 128, 1);
}

// Round 4
// 634.559 us; speedup vs baseline: 1.4338x; 1.0509x over previous
//
#include <hip/hip_runtime.h>
#include <cstdint>
#include <cstddef>

// QRNN fused pipeline for MI355X (gfx950).
// B=32, S=2048, D_in=512, D_model=1024, D_mlp=1024, n_cls=128.
//
// ws layout (bytes): U bf16 [2048][1024] @0 (4MB) | Fagg @4MB | Zagg @6MB |
//   h @8MB | q0 @8MB+256K | q1 @8MB+512K | zero page @12MB (4KB) | xb bf16 @16MB (64MB)
//
// qrnn_main8 (round 4): 256x256 tile, 8 waves, BK=32, ring-4 LDS (4 x 32KB),
// depth-3 gload_lds staging. ONE s_barrier + ONE counted vmcnt per K-step;
// ds_reads for the next phase/kstep are issued BEHIND the MFMA clusters in
// the same window so the LDS pipe and matrix pipe run concurrently from each
// wave's in-order issue stream (AITER-style; round-3's 4-barrier lockstep
// serialized all pipes at ~27% each).
//   kstep t: vmcnt(4) [tile t+1 landed]; BAR;
//            read afrH(t) | gloadA(t+3) | 16 MFMA accL (ops preread) |
//            gloadB(t+3) | read bfr/afrL(t+1) | 16 MFMA accH
// Ping-pong register sets via unroll-by-2 (rule #20: all indices static).
// XCD-chunked swizzle (T1, kept from round 3: FETCH 541->165 MB).
// LDS conflict-freedom: slot swizzle on pre-swizzled global source + reads.
// xprev shift structural: ksteps 0..15 x[t]*W-half, 16..31 x[t-1]*V-half.

typedef __attribute__((ext_vector_type(8))) short short8;
typedef __attribute__((ext_vector_type(4))) float f32x4;

#define ZERO_OFF_E 6291456u    // 12MB / 2 (bf16 elements)
#define XB_OFF_E   8388608u    // 16MB / 2
#define U_LDS_BASE 8256        // (old fallback kernel) A stage = 129 rows * 64B

__device__ __forceinline__ unsigned short f2bf(float f) {
  unsigned int u = __float_as_uint(f);
  u += 0x7fffu + ((u >> 16) & 1u);
  return (unsigned short)(u >> 16);
}

__device__ __forceinline__ unsigned stage_addr(int r, int c) {
  return (unsigned)(r * 64 + (((c + r + (r >> 2)) & 3) << 4));
}

__device__ __forceinline__ float sigmoidf_fast(float x) {
  return 1.f / (1.f + __expf(-x));
}
__device__ __forceinline__ float tanhf_fast(float x) {
  float a = fabsf(x);
  float e = __expf(-2.f * a);
  float t = (1.f - e) / (1.f + e);
  return copysignf(t, x);
}

// async 16B global->LDS. LDS dest must be wave-uniform base; lane lands at
// base + lane*16.
__device__ __forceinline__ void gload_lds16(const void* g, const char* lds) {
  __builtin_amdgcn_global_load_lds(
      (const __attribute__((address_space(1))) void*)(uintptr_t)g,
      (__attribute__((address_space(3))) void*)(uint32_t)(uintptr_t)lds, 16, 0, 0);
}

// ---------------- prologue ----------------
// grid 8833: [0,8192) pack_x (4 float4/thread); [8192,8704) pack_u; [8704,8832) init; 8832 zpg
__global__ void prologue_kernel(const float* __restrict__ x, const float* __restrict__ W,
                                const float* __restrict__ V,
                                const float* __restrict__ b0, const float* __restrict__ b1,
                                const float* __restrict__ b2,
                                unsigned short* __restrict__ xb, unsigned short* __restrict__ U,
                                float* __restrict__ q0, float* __restrict__ q1,
                                float* __restrict__ out, uint4* __restrict__ zpg) {
  __shared__ float T[64 * 65];
  const int bx = blockIdx.x;
  if (bx < 8192) {
    int base = bx * 1024 + threadIdx.x;
#pragma unroll
    for (int i = 0; i < 4; ++i) {
      int gid = base + i * 256;
      float4 v = ((const float4*)x)[gid];
      ushort4 o;
      o.x = f2bf(v.x); o.y = f2bf(v.y); o.z = f2bf(v.z); o.w = f2bf(v.w);
      ((ushort4*)xb)[gid] = o;
    }
  } else if (bx < 8704) {
    const int u = bx - 8192;
    const int j0 = (u & 31) * 64;
    const int k0 = (u >> 5) * 64;
    const int jl = threadIdx.x & 63;
    const int q  = threadIdx.x >> 6;
    const float* src = (k0 < 512) ? (W + (size_t)k0 * 3072) : (V + (size_t)(k0 - 512) * 3072);
#pragma unroll 4
    for (int i = 0; i < 16; ++i) {
      int kl = q * 16 + i;
      T[kl * 65 + jl] = src[(size_t)kl * 3072 + j0 + jl];
    }
    __syncthreads();
    const int kl = threadIdx.x & 63;
#pragma unroll 4
    for (int i = 0; i < 16; ++i) {
      int jj = q * 16 + i;
      U[(size_t)(j0 + jj) * 1024 + k0 + kl] = f2bf(T[kl * 65 + jj]);
    }
  } else if (bx < 8832) {
    int gid = (bx - 8704) * 256 + threadIdx.x;   // 32768
    q0[gid] = b0[gid & 1023];
    q1[gid] = b1[gid & 1023];
    if (gid < 4096) out[gid] = b2[gid & 127];
  } else {
    zpg[threadIdx.x] = make_uint4(0u, 0u, 0u, 0u);   // 4 KB zeros
  }
}

// ---------------- main (bf16 path): 256^2 8-wave single-barrier pipeline ----------------
// grid 2048 (1D, XCD-chunked), block 512 (waves: wm=wid>>2 x wn=wid&3)
// per wave: 128 t-rows x 64 cols -> acc[8][4] f32x4.
__global__ __launch_bounds__(512, 2) void qrnn_main8(
    const unsigned short* __restrict__ wsb, const float* __restrict__ Vb,
    float* __restrict__ Fagg, float* __restrict__ Zagg) {
  __shared__ __align__(16) char smem[131072];

  // XCD-chunked swizzle: nwg=2048, nwg%8==0 -> bijective. Blocks with the same
  // (b,cj) A-panel (consecutive orig, dt fastest) land on the SAME XCD.
  const int bid  = blockIdx.x;
  const int orig = (bid & 7) * 256 + (bid >> 3);
  const int dt = orig & 7;
  const int cj = (orig >> 3) & 7;
  const int b  = orig >> 6;

  const int tid = threadIdx.x;
  const int lane = tid & 63;
  const int wid  = tid >> 6;
  const int wm = wid >> 2, wn = wid & 3;
  const int l15 = lane & 15, lc = lane >> 4;
  const int s0 = cj * 256;

  f32x4 acc[8][4];
#pragma unroll
  for (int i = 0; i < 8; ++i)
#pragma unroll
    for (int j = 0; j < 4; ++j) acc[i][j] = f32x4{0.f, 0.f, 0.f, 0.f};

  // ---- per-lane staging source offsets (bf16 elements rel. wsb) ----
  unsigned eAx[2], eAp[2], eB[2];
#pragma unroll
  for (int i = 0; i < 2; ++i) {
    int row_g = wid * 32 + i * 16 + (lane >> 2);
    int q = (lane & 3) ^ ((row_g >> 1) & 3);
    int tx = s0 + row_g;                       // ksteps 0..15: x[t]
    eAx[i] = XB_OFF_E + (unsigned)(b * 2048 + tx) * 512u + (unsigned)(q * 8);
    int tp = s0 - 1 + row_g;                   // ksteps 16..31: x[t-1]
    eAp[i] = (tp < 0) ? (ZERO_OFF_E + (unsigned)(q * 8))
                      : (XB_OFF_E + (unsigned)(b * 2048 + tp) * 512u + (unsigned)(q * 8));
    int jj = (row_g < 128) ? (dt * 128 + row_g) : (1024 + dt * 128 + (row_g - 128));
    eB[i] = (unsigned)jj * 1024u + (unsigned)(q * 8);
  }

  // ---- fragment read offsets (swizzle lc ^ ((l15>>1)&3)) ----
  const unsigned swz = (unsigned)((lc ^ ((l15 >> 1) & 3)) << 4);
  const unsigned oA = (unsigned)((wm * 128 + l15) * 64) + swz;            // A rows
  const unsigned oB = 16384u + (unsigned)((wn * 64 + l15) * 64) + swz;    // B rows

  auto stage_half = [&](int kt, int h) {
    const unsigned sbase = (unsigned)((kt & 3) << 15);
    if (h == 0) {
      const unsigned kaddA = (kt < 16) ? (unsigned)(kt * 32) : (unsigned)((kt - 16) * 32);
      const bool xp = (kt < 16);
#pragma unroll
      for (int i = 0; i < 2; ++i) {
        unsigned da = (unsigned)__builtin_amdgcn_readfirstlane(
            (int)(sbase + (unsigned)(wid * 2048 + i * 1024)));
        gload_lds16(wsb + ((xp ? eAx[i] : eAp[i]) + kaddA), smem + da);
      }
    } else {
      const unsigned kaddB = (unsigned)(kt * 32);
#pragma unroll
      for (int i = 0; i < 2; ++i) {
        unsigned db = (unsigned)__builtin_amdgcn_readfirstlane(
            (int)(sbase + 16384u + (unsigned)(wid * 2048 + i * 1024)));
        gload_lds16(wsb + (eB[i] + kaddB), smem + db);
      }
    }
  };

  // ---- pipeline prologue: slots 0..2 in flight (12 gloads); wait tile0 ----
  stage_half(0, 0); stage_half(0, 1);
  stage_half(1, 0); stage_half(1, 1);
  stage_half(2, 0); stage_half(2, 1);
  asm volatile("s_waitcnt vmcnt(8)" ::: "memory");
  __builtin_amdgcn_s_barrier();

  short8 bC[4], aC[4], bN[4], aN[4], aH[4];
  // preload kt=0 low-half operands from slot 0
#pragma unroll
  for (int nt = 0; nt < 4; ++nt) bC[nt] = *(const short8*)(smem + oB + nt * 1024);
#pragma unroll
  for (int m = 0; m < 4; ++m)   aC[m]  = *(const short8*)(smem + oA + m * 1024);

  // One K-step, single barrier + single counted vmcnt. Bc/Ac: this kstep's
  // low-half operands (preread). Bn/An: next kstep's, read behind accH MFMAs.
#define KSTEP(KT, Bc, Ac, Bn, An)                                                   \
  {                                                                                 \
    const int kt = (KT);                                                            \
    if (kt <= 29) asm volatile("s_waitcnt vmcnt(4)" ::: "memory");                  \
    else          asm volatile("s_waitcnt vmcnt(0)" ::: "memory");                  \
    __builtin_amdgcn_s_barrier();                                                   \
    const char* buf  = smem + ((kt & 3) << 15);                                     \
    const char* bufn = smem + (((kt + 1) & 3) << 15);                               \
    /* afrH reads land under the accL MFMA cluster */                               \
    _Pragma("unroll")                                                               \
    for (int m = 0; m < 4; ++m) aH[m] = *(const short8*)(buf + oA + (m + 4) * 1024);\
    if (kt < 29) stage_half(kt + 3, 0);                                             \
    __builtin_amdgcn_s_setprio(1);                                                  \
    _Pragma("unroll")                                                               \
    for (int m = 0; m < 4; ++m)                                                     \
      _Pragma("unroll")                                                             \
      for (int nt = 0; nt < 4; ++nt)                                                \
        acc[m][nt] =                                                                \
            __builtin_amdgcn_mfma_f32_16x16x32_bf16(Ac[m], Bc[nt], acc[m][nt], 0, 0, 0); \
    __builtin_amdgcn_s_setprio(0);                                                  \
    if (kt < 29) stage_half(kt + 3, 1);                                             \
    /* next-kstep operand reads land under the accH MFMA cluster */                 \
    if (kt < 31) {                                                                  \
      _Pragma("unroll")                                                             \
      for (int nt = 0; nt < 4; ++nt) Bn[nt] = *(const short8*)(bufn + oB + nt * 1024); \
      _Pragma("unroll")                                                             \
      for (int m = 0; m < 4; ++m)   An[m]  = *(const short8*)(bufn + oA + m * 1024);\
    }                                                                               \
    __builtin_amdgcn_s_setprio(1);                                                  \
    _Pragma("unroll")                                                               \
    for (int m = 0; m < 4; ++m)                                                     \
      _Pragma("unroll")                                                             \
      for (int nt = 0; nt < 4; ++nt)                                                \
        acc[m + 4][nt] =                                                            \
            __builtin_amdgcn_mfma_f32_16x16x32_bf16(aH[m], Bc[nt], acc[m + 4][nt], 0, 0, 0); \
    __builtin_amdgcn_s_setprio(0);                                                  \
  }

#pragma unroll 1
  for (int k2 = 0; k2 < 32; k2 += 2) {
    KSTEP(k2,     bC, aC, bN, aN);
    KSTEP(k2 + 1, bN, aN, bC, aC);
  }
#undef KSTEP

  // ---- fused activations + scan: 4 phases of 64 timesteps, 128 d ----
  // ph fully unrolled (rule #20: acc indices must be compile-time constants).
  float* fA   = (float*)smem;                    // [64][132]
  float* tzA  = (float*)(smem + 33792);          // [64][132]
  float* segF = (float*)(smem + 67584);          // [4][128]
  float* segZ = (float*)(smem + 69632);          // [4][128]

  float vb[4];
#pragma unroll
  for (int nt = 0; nt < 4; ++nt)
    vb[nt] = Vb[(wn >> 1) * 1024 + dt * 128 + (wn & 1) * 64 + nt * 16 + l15];

  const int d = tid & 127;
  const int seg = tid >> 7;
  float F_run = 1.f, Z_run = 0.f;

#pragma unroll
  for (int ph = 0; ph < 4; ++ph) {
    __syncthreads();
    if (wm == (ph >> 1)) {
      float* dst = (wn < 2) ? fA : tzA;
#pragma unroll
      for (int m = 0; m < 4; ++m) {
#pragma unroll
        for (int nt = 0; nt < 4; ++nt)
#pragma unroll
          for (int rg = 0; rg < 4; ++rg) {
            int t = m * 16 + (lc << 2) + rg;          // phase-local 0..63
            int c = (wn & 1) * 64 + nt * 16 + l15;    // 0..127
            float v = acc[(ph & 1) * 4 + m][nt][rg] + vb[nt];
            v = (wn < 2) ? sigmoidf_fast(v) : tanhf_fast(v);
            dst[t * 132 + c] = v;
          }
      }
    }
    __syncthreads();
    {
      float F = 1.f, Z = 0.f;
#pragma unroll 4
      for (int i = 0; i < 16; ++i) {
        int t = seg * 16 + i;
        float f  = fA[t * 132 + d];
        float tz = tzA[t * 132 + d];
        float z = (1.f - f) * tz;
        Z = f * Z + z;
        F *= f;
      }
      segF[seg * 128 + d] = F;
      segZ[seg * 128 + d] = Z;
    }
    __syncthreads();
    if (tid < 128) {
#pragma unroll
      for (int sgi = 0; sgi < 4; ++sgi) {
        float Fs = segF[sgi * 128 + tid], Zs = segZ[sgi * 128 + tid];
        Z_run = Fs * Z_run + Zs;
        F_run *= Fs;
      }
    }
  }
  if (tid < 128) {
    size_t o = (((size_t)b * 8 + cj) << 10) + dt * 128 + tid;
    Fagg[o] = F_run;
    Zagg[o] = Z_run;
  }
}

// ---------------- fallback (f32 path, 16-chunk layout) — previous verified kernel ----------------
template <bool USE_BF>
__global__ __launch_bounds__(256, 3) void qrnn_main(
    const unsigned short* __restrict__ wsb, const float* __restrict__ xf,
    const float* __restrict__ Vb,
    float* __restrict__ Fagg, float* __restrict__ Zagg) {
  __shared__ __align__(16) char smem[36864];

  const int dt = blockIdx.x;
  const int cj = blockIdx.y;
  const int b  = blockIdx.z;
  const int tid = threadIdx.x;
  const int lane = tid & 63;
  const int wid  = tid >> 6;
  const int wm = wid >> 1, wn = wid & 1;
  const int s0 = cj * 128;
  const int l15 = lane & 15, lc = lane >> 4;

  f32x4 acc[4][4];
#pragma unroll
  for (int i = 0; i < 4; ++i)
#pragma unroll
    for (int j = 0; j < 4; ++j) acc[i][j] = f32x4{0.f, 0.f, 0.f, 0.f};

  unsigned voffA[2];
  size_t offAF[2]; int zAF[2];
#pragma unroll
  for (int p = 0; p < 2; ++p) {
    int cw = tid + p * 256;
    int r = cw >> 2, c = cw & 3;
    int sg = s0 - 1 + r;
    voffA[p] = (sg < 0) ? (ZERO_OFF_E + (unsigned)(c * 8))
                        : (XB_OFF_E + (unsigned)(b * 2048 + sg) * 512u + (unsigned)(c * 8));
    zAF[p] = (sg < 0);
    offAF[p] = ((size_t)(b * 2048 + (sg < 0 ? 0 : sg)) << 9) + c * 8;
  }
  unsigned voffA3 = XB_OFF_E + (unsigned)(b * 2048 + s0 + 127) * 512u + (unsigned)((tid & 3) * 8);
  size_t offAF3 = ((size_t)(b * 2048 + s0 + 127) << 9) + (tid & 3) * 8;

  unsigned voffU[4];
#pragma unroll
  for (int k = 0; k < 4; ++k) {
    int uw = tid + k * 256;
    int r = uw >> 2, c = uw & 3;
    int col = r & 127, half = r >> 7;
    int j = (col < 64) ? (dt * 64 + col) : (1024 + dt * 64 + (col - 64));
    voffU[k] = (unsigned)(j * 1024 + half * 512 + c * 8);
  }

  unsigned wA[2], wU[4];
#pragma unroll
  for (int p = 0; p < 2; ++p) {
    int cw = tid + p * 256;
    wA[p] = stage_addr(cw >> 2, cw & 3);
  }
  const unsigned wA3 = stage_addr(128, tid & 3);
#pragma unroll
  for (int k = 0; k < 4; ++k) {
    int uw = tid + k * 256;
    wU[k] = U_LDS_BASE + stage_addr(uw >> 2, uw & 3);
  }

  unsigned roA[2][4], roU[2][4];
#pragma unroll
  for (int h2 = 0; h2 < 2; ++h2) {
#pragma unroll
    for (int mt = 0; mt < 4; ++mt) {
      int rr = wm * 64 + l15 + mt * 16 + 1 - h2;
      roA[h2][mt] = stage_addr(rr, lc);
    }
#pragma unroll
    for (int nt = 0; nt < 4; ++nt) {
      int rrU = h2 * 128 + wn * 64 + l15 + nt * 16;
      roU[h2][nt] = U_LDS_BASE + stage_addr(rrU, lc);
    }
  }

  uint4 pA0, pA1, pA3, pU0, pU1, pU2, pU3;

  auto load_stage = [&](int s) {
    const unsigned short* cur = wsb + s * 32;
    if constexpr (USE_BF) {
      pA0 = *(const uint4*)(cur + voffA[0]);
      pA1 = *(const uint4*)(cur + voffA[1]);
      if (tid < 4) pA3 = *(const uint4*)(cur + voffA3);
    } else {
      const float* curf = xf + s * 32;
#pragma unroll
      for (int p = 0; p < 2; ++p) {
        uint4 v = make_uint4(0u, 0u, 0u, 0u);
        if (!zAF[p]) {
          float4 a0 = *(const float4*)(curf + offAF[p]);
          float4 a1 = *(const float4*)(curf + offAF[p] + 4);
          v.x = (unsigned)f2bf(a0.x) | ((unsigned)f2bf(a0.y) << 16);
          v.y = (unsigned)f2bf(a0.z) | ((unsigned)f2bf(a0.w) << 16);
          v.z = (unsigned)f2bf(a1.x) | ((unsigned)f2bf(a1.y) << 16);
          v.w = (unsigned)f2bf(a1.z) | ((unsigned)f2bf(a1.w) << 16);
        }
        if (p == 0) pA0 = v; else pA1 = v;
      }
      if (tid < 4) {
        float4 a0 = *(const float4*)(curf + offAF3);
        float4 a1 = *(const float4*)(curf + offAF3 + 4);
        pA3.x = (unsigned)f2bf(a0.x) | ((unsigned)f2bf(a0.y) << 16);
        pA3.y = (unsigned)f2bf(a0.z) | ((unsigned)f2bf(a0.w) << 16);
        pA3.z = (unsigned)f2bf(a1.x) | ((unsigned)f2bf(a1.y) << 16);
        pA3.w = (unsigned)f2bf(a1.z) | ((unsigned)f2bf(a1.w) << 16);
      }
    }
    pU0 = *(const uint4*)(cur + voffU[0]);
    pU1 = *(const uint4*)(cur + voffU[1]);
    pU2 = *(const uint4*)(cur + voffU[2]);
    pU3 = *(const uint4*)(cur + voffU[3]);
  };

  load_stage(0);

#pragma unroll 1
  for (int s = 0; s < 16; ++s) {
    __syncthreads();
    *(uint4*)(smem + wA[0]) = pA0;
    *(uint4*)(smem + wA[1]) = pA1;
    if (tid < 4) *(uint4*)(smem + wA3) = pA3;
    *(uint4*)(smem + wU[0]) = pU0;
    *(uint4*)(smem + wU[1]) = pU1;
    *(uint4*)(smem + wU[2]) = pU2;
    *(uint4*)(smem + wU[3]) = pU3;
    __syncthreads();
    if (s < 15) load_stage(s + 1);
#pragma unroll
    for (int h2 = 0; h2 < 2; ++h2) {
      short8 bfr[4];
#pragma unroll
      for (int nt = 0; nt < 4; ++nt)
        bfr[nt] = *(const short8*)(smem + roU[h2][nt]);
#pragma unroll
      for (int mt = 0; mt < 4; ++mt) {
        short8 afr = *(const short8*)(smem + roA[h2][mt]);
#pragma unroll
        for (int nt = 0; nt < 4; ++nt)
          acc[mt][nt] = __builtin_amdgcn_mfma_f32_16x16x32_bf16(afr, bfr[nt], acc[mt][nt], 0, 0, 0);
      }
    }
  }

  float* fA   = (float*)smem;
  float* tzA  = (float*)(smem + 17408);
  float* segF = (float*)(smem + 34816);
  float* segZ = (float*)(smem + 35840);

  const int d = tid & 63;
  float vb[4];
#pragma unroll
  for (int nt = 0; nt < 4; ++nt)
    vb[nt] = Vb[wn * 1024 + dt * 64 + nt * 16 + l15];

  float F_run = 1.f, Z_run = 0.f;

  for (int ph = 0; ph < 2; ++ph) {
    __syncthreads();
    if (wm == ph) {
      float* dst = (wn == 0) ? fA : tzA;
#pragma unroll
      for (int mt = 0; mt < 4; ++mt)
#pragma unroll
        for (int nt = 0; nt < 4; ++nt)
#pragma unroll
          for (int rg = 0; rg < 4; ++rg) {
            int t = mt * 16 + ((lane >> 4) << 2) + rg;
            int c = nt * 16 + l15;
            float v = acc[mt][nt][rg] + vb[nt];
            v = (wn == 0) ? sigmoidf_fast(v) : tanhf_fast(v);
            dst[t * 68 + c] = v;
          }
    }
    __syncthreads();
    {
      int seg = tid >> 6;
      float F = 1.f, Z = 0.f;
#pragma unroll 4
      for (int i = 0; i < 16; ++i) {
        int t = seg * 16 + i;
        float f  = fA[t * 68 + d];
        float tz = tzA[t * 68 + d];
        float z = (1.f - f) * tz;
        Z = f * Z + z;
        F *= f;
      }
      segF[seg * 64 + d] = F;
      segZ[seg * 64 + d] = Z;
    }
    __syncthreads();
    if (tid < 64) {
#pragma unroll
      for (int sgi = 0; sgi < 4; ++sgi) {
        float Fs = segF[sgi * 64 + tid], Zs = segZ[sgi * 64 + tid];
        Z_run = Fs * Z_run + Zs;
        F_run *= Fs;
      }
    }
  }
  if (tid < 64) {
    size_t o = (((size_t)b * 16 + cj) << 10) + dt * 64 + tid;
    Fagg[o] = F_run;
    Zagg[o] = Z_run;
  }
}

// ---------------- head: K-split o-gate + nch-chunk combine ----------------
// grid (16 dtile, 32 b), block 256 = 64 d x 4 k-segments
__global__ void head_kernel(const float* __restrict__ x, const float* __restrict__ W,
                            const float* __restrict__ V, const float* __restrict__ Vb,
                            const float* __restrict__ Fagg, const float* __restrict__ Zagg,
                            float* __restrict__ h, int nch) {
  __shared__ float red[4][64];
  const int dl = threadIdx.x & 63;
  const int w  = threadIdx.x >> 6;
  const int d = blockIdx.x * 64 + dl;
  const int b = blockIdx.y;

  const float* xl = x + ((size_t)b * 2048 + 2047) * 512;
  const float* xp = xl - 512;
  const float* Wc = W + 2048 + d;
  const float* Vc = V + 2048 + d;
  float po = 0.f;
  const int k0 = w * 128;
#pragma unroll 8
  for (int k = k0; k < k0 + 128; ++k) {
    po += xl[k] * Wc[(size_t)k * 3072];
    po += xp[k] * Vc[(size_t)k * 3072];
  }
  red[w][dl] = po;
  __syncthreads();
  if (w == 0) {
    po = red[0][dl] + red[1][dl] + red[2][dl] + red[3][dl] + Vb[2048 + d];
    float c = 0.f;
    for (int j = 0; j < nch; ++j) {
      size_t o = (((size_t)b * nch + j) << 10) + d;
      c = Fagg[o] * c + Zagg[o];
    }
    h[((size_t)b << 10) + d] = c * sigmoidf_fast(po);
  }
}

// ---------------- MLP: K-split atomic GEMV (ReLU on input) ----------------
// grid (N/64, B, 4 ksplit), block 256 = 64 n x 4 waves
__global__ void mlp_atomic_kernel(const float* __restrict__ in, const float* __restrict__ Wt,
                                  float* __restrict__ out, int K, int N, int relu_in) {
  __shared__ float red[4][64];
  const int nl = threadIdx.x & 63;
  const int w  = threadIdx.x >> 6;
  const int n = blockIdx.x * 64 + nl;
  const int b = blockIdx.y;
  const int k0 = blockIdx.z * (K >> 2) + w * (K >> 4);
  const float* row = in + (size_t)b * K;
  const float* Wc = Wt + n;
  float s = 0.f;
#pragma unroll 8
  for (int k = k0; k < k0 + (K >> 4); ++k) {
    float v = row[k];
    if (relu_in) v = fmaxf(v, 0.f);
    s += v * Wc[(size_t)k * N];
  }
  red[w][nl] = s;
  __syncthreads();
  if (w == 0) {
    s = red[0][nl] + red[1][nl] + red[2][nl] + red[3][nl];
    atomicAdd(&out[(size_t)b * N + n], s);
  }
}

extern "C" void kernel_launch(void* const* d_in, const int* in_sizes, int n_in,
                              void* d_out, int out_size, void* d_ws, size_t ws_size,
                              hipStream_t stream) {
  const float* x  = (const float*)d_in[0];
  const float* W  = (const float*)d_in[1];
  const float* V  = (const float*)d_in[2];
  const float* Vb = (const float*)d_in[3];
  const float* W0 = (const float*)d_in[4];
  const float* b0 = (const float*)d_in[5];
  const float* W1 = (const float*)d_in[6];
  const float* b1 = (const float*)d_in[7];
  const float* W2 = (const float*)d_in[8];
  const float* b2 = (const float*)d_in[9];

  char* ws = (char*)d_ws;
  unsigned short* U = (unsigned short*)(ws);                              // 4 MiB
  float* Fagg = (float*)(ws + (size_t)4 * 1024 * 1024);                   // 2 MiB
  float* Zagg = (float*)(ws + (size_t)6 * 1024 * 1024);                   // 2 MiB
  float* h    = (float*)(ws + (size_t)8 * 1024 * 1024);                   // 128 KiB
  float* q0   = (float*)(ws + (size_t)8 * 1024 * 1024 + 256 * 1024);
  float* q1   = (float*)(ws + (size_t)8 * 1024 * 1024 + 512 * 1024);
  uint4* zpg  = (uint4*)(ws + (size_t)12 * 1024 * 1024);                  // 4 KiB zeros
  unsigned short* xb = (unsigned short*)(ws + (size_t)16 * 1024 * 1024);  // 64 MiB

  const size_t need_bf = (size_t)16 * 1024 * 1024 + (size_t)67108864;
  int use_bf = (ws_size >= need_bf) ? 1 : 0;   // constant across calls -> graph-safe

  prologue_kernel<<<8833, 256, 0, stream>>>(x, W, V, b0, b1, b2, xb, U, q0, q1,
                                            (float*)d_out, zpg);
  if (use_bf) {
    qrnn_main8<<<2048, 512, 0, stream>>>((const unsigned short*)ws, Vb, Fagg, Zagg);
    head_kernel<<<dim3(16, 32), 256, 0, stream>>>(x, W, V, Vb, Fagg, Zagg, h, 8);
  } else {
    qrnn_main<false><<<dim3(16, 16, 32), 256, 0, stream>>>((const unsigned short*)ws, x,
                                                           Vb, Fagg, Zagg);
    head_kernel<<<dim3(16, 32), 256, 0, stream>>>(x, W, V, Vb, Fagg, Zagg, h, 16);
  }
  mlp_atomic_kernel<<<dim3(16, 32, 4), 256, 0, stream>>>(h, W0, q0, 1024, 1024, 0);
  mlp_atomic_kernel<<<dim3(16, 32, 4), 256, 0, stream>>>(q0, W1, q1, 1024, 1024, 1);
  mlp_atomic_kernel<<<dim3(2, 32, 4), 256, 0, stream>>>(q1, W2, (float*)d_out, 1024, 128, 1);
}